// Round 20
// baseline (322.767 us; speedup 1.0000x reference)
//
#include <hip/hip_runtime.h>

typedef float f32x4 __attribute__((ext_vector_type(4)));
typedef _Float16 f16x2 __attribute__((ext_vector_type(2)));
typedef _Float16 f16x4 __attribute__((ext_vector_type(4)));
typedef _Float16 f16x8 __attribute__((ext_vector_type(8)));

// async global->LDS, 16B per lane; LDS dest = wave-uniform base + lane*16B
__device__ __forceinline__ void gload_lds16(const _Float16* g, _Float16* l) {
  __builtin_amdgcn_global_load_lds(
      (const __attribute__((address_space(1))) unsigned int*)g,
      (__attribute__((address_space(3))) unsigned int*)l, 16, 0, 0);
}

// ================= CSR build =================
__global__ __launch_bounds__(256) void hist_kernel(const int* __restrict__ dst,
                                                   int* __restrict__ deg, int E) {
  int e = blockIdx.x * 256 + threadIdx.x;
  if (e < E) atomicAdd(&deg[dst[e]], 1);
}

__global__ __launch_bounds__(1024) void scan_kernel(const int* __restrict__ deg,
                                                    int* __restrict__ rowstart,
                                                    int* __restrict__ cursor, int N) {
  __shared__ int sums[1024];
  const int t = threadIdx.x;
  const int CH = (N + 1023) >> 10;
  int local[32];
  int base = t * CH;
  int s = 0;
  for (int i = 0; i < CH; i++) {
    int idx = base + i;
    int v = (idx < N) ? deg[idx] : 0;
    local[i] = s;
    s += v;
  }
  sums[t] = s;
  __syncthreads();
  for (int off = 1; off < 1024; off <<= 1) {
    int add = (t >= off) ? sums[t - off] : 0;
    __syncthreads();
    sums[t] += add;
    __syncthreads();
  }
  int prefix = sums[t] - s;
  for (int i = 0; i < CH; i++) {
    int idx = base + i;
    if (idx < N) {
      int v = prefix + local[i];
      rowstart[idx] = v;
      cursor[idx] = v;
    }
  }
  if (t == 1023) rowstart[N] = sums[1023];
}

__global__ __launch_bounds__(256) void fill_kernel(const int* __restrict__ src,
                                                   const int* __restrict__ dst,
                                                   int* __restrict__ cursor,
                                                   int* __restrict__ nbr, int E) {
  int e = blockIdx.x * 256 + threadIdx.x;
  if (e >= E) return;
  int pos = atomicAdd(&cursor[dst[e]], 1);
  nbr[pos] = src[e];
}

// ========= x0 fp32 -> fp16, fused with zeroing deg + stats/pooled =========
__global__ __launch_bounds__(256) void xprep_kernel(const float4* __restrict__ in,
                                                    f16x4* __restrict__ out, int n4,
                                                    int* __restrict__ deg, int N,
                                                    float* __restrict__ zbuf, int zn) {
  int i = blockIdx.x * 256 + threadIdx.x;
  if (i < N) deg[i] = 0;
  if (i < zn) zbuf[i] = 0.f;
  if (i >= n4) return;
  float4 v = in[i];
  f16x4 h;
  h[0] = (_Float16)v.x; h[1] = (_Float16)v.y;
  h[2] = (_Float16)v.z; h[3] = (_Float16)v.w;
  out[i] = h;
}

// ====== gather over fp16 rows; BN fold (from raw sums) + ReLU fused; fp16 output ======
template <int C, bool BNIN>
__global__ __launch_bounds__(256) void gather_agg_kernel(
    const _Float16* __restrict__ x, const int* __restrict__ rowstart,
    const int* __restrict__ nbr, const float* __restrict__ stats,
    const float* __restrict__ gamma, const float* __restrict__ beta,
    _Float16* __restrict__ agg, int N, float invN) {
  constexpr int Din = 64 * C;
  const int wave = threadIdx.x >> 6;
  const int lane = threadIdx.x & 63;
  const int node = blockIdx.x * 4 + wave;
  if (node >= N) return;

  float sc[C], sh[C];
  if constexpr (BNIN) {
#pragma unroll
    for (int j = 0; j < C; j++) {
      int c = lane * C + j;
      float mean = stats[c] * invN;
      float var = stats[Din + c] * invN - mean * mean;
      sc[j] = rsqrtf(var + 1e-5f) * gamma[c];
      sh[j] = beta[c] - mean * sc[j];
    }
  }

#define LOADROW(dstv, rowidx)                                              \
  {                                                                        \
    const _Float16* _p = x + (size_t)(rowidx)*Din + lane * C;              \
    if constexpr (C == 2) {                                                \
      f16x2 _t = *(const f16x2*)_p;                                        \
      dstv[0] = (float)_t[0]; dstv[1] = (float)_t[1];                      \
    } else {                                                               \
      f16x4 _t = *(const f16x4*)_p;                                        \
      dstv[0] = (float)_t[0]; dstv[1] = (float)_t[1];                      \
      dstv[2] = (float)_t[2]; dstv[3] = (float)_t[3];                      \
    }                                                                      \
  }
#define ACCUM(vv)                                                          \
  _Pragma("unroll") for (int j = 0; j < C; j++)                            \
      acc[j] += BNIN ? fmaxf(vv[j] * sc[j] + sh[j], 0.f) : vv[j];

  float acc[C];
  {
    float v[C];
    LOADROW(v, node)
#pragma unroll
    for (int j = 0; j < C; j++)
      acc[j] = BNIN ? fmaxf(v[j] * sc[j] + sh[j], 0.f) : v[j];
  }
  const int rs = rowstart[node], re = rowstart[node + 1];
  int e = rs;
  for (; e + 3 < re; e += 4) {
    int s0 = nbr[e], s1 = nbr[e + 1], s2 = nbr[e + 2], s3 = nbr[e + 3];
    float v0[C], v1[C], v2[C], v3[C];
    LOADROW(v0, s0)
    LOADROW(v1, s1)
    LOADROW(v2, s2)
    LOADROW(v3, s3)
    ACCUM(v0) ACCUM(v1) ACCUM(v2) ACCUM(v3)
  }
  for (; e + 1 < re; e += 2) {
    int s0 = nbr[e], s1 = nbr[e + 1];
    float v0[C], v1[C];
    LOADROW(v0, s0)
    LOADROW(v1, s1)
    ACCUM(v0) ACCUM(v1)
  }
  if (e < re) {
    int s0 = nbr[e];
    float v0[C];
    LOADROW(v0, s0)
    ACCUM(v0)
  }
#undef ACCUM
#undef LOADROW

  _Float16* o = agg + (size_t)node * Din + lane * C;
  if constexpr (C == 2) {
    f16x2 r; r[0] = (_Float16)acc[0]; r[1] = (_Float16)acc[1];
    *(f16x2*)o = r;
  } else {
    f16x4 r;
    r[0] = (_Float16)acc[0]; r[1] = (_Float16)acc[1];
    r[2] = (_Float16)acc[2]; r[3] = (_Float16)acc[3];
    *(f16x4*)o = r;
  }
}

// ================= batched weight prep: W[K][N] fp32 -> WT [N][K] fp16 =================
struct WSeg {
  const float* W;
  _Float16* TH;
  int K, N, total;
};
struct WAll { WSeg s[6]; };

__global__ __launch_bounds__(256) void wprep_all_kernel(WAll a) {
  WSeg sg = a.s[blockIdx.y];
  int idx = blockIdx.x * 256 + threadIdx.x;
  if (idx >= sg.total) return;
  int k = idx / sg.N, n = idx - k * sg.N;
  sg.TH[(size_t)n * sg.K + k] = (_Float16)sg.W[idx];
}

// ===== MFMA GEMM: C = A[MxK] @ B[KxN] + bias, all-FP16 (fp32 accumulate) =====
// RT=32 rows x 128 cols per block, 4 waves, BK=64; XCD swizzle.
// A staged via global_load_lds (pre-swizzled per-lane sources, fragment-linear LDS),
// double-buffered, prefetch issued BEFORE compute, ONE barrier per K-step.
template <int RT>
__global__ __launch_bounds__(256, 8) void gemm_mfma_kernel(
    const _Float16* __restrict__ A, const _Float16* __restrict__ BT,
    const float* __restrict__ bias, _Float16* __restrict__ Ch,
    int M, int K, int N, int mblocks, int cbShift,
    int doRelu, float* __restrict__ stats) {
  constexpr int NF = RT / 16;   // row frags per 32-K half
  constexpr int NFT = 2 * NF;   // frags per 64-K step
  constexpr int FPW = NFT / 4;  // frags staged per wave
  __shared__ _Float16 Ah[2][NFT * 512];
  const int bid = blockIdx.x;
  const int xcd = bid & 7;
  const int q = bid >> 3;
  const int r = ((q >> cbShift) << 3) + xcd;
  const int cb = q & ((1 << cbShift) - 1);
  if (r >= mblocks) return;

  const int tid = threadIdx.x;
  const int lane = tid & 63;
  const int w = tid >> 6;
  const int rowBase = r * RT;
  const int colBase = cb * 128 + w * 32;

  f32x4 acc[NF][2] = {};
  const int c0 = colBase + (lane & 15);
  const int kfrag = (lane >> 4) * 8;

  // pre-swizzled per-lane global source offsets (one per staged fragment)
  size_t srcOff[FPW];
#pragma unroll
  for (int i = 0; i < FPW; i++) {
    int F = w * FPW + i;          // fragment index: F = ks*NF + fi
    int ks = F / NF, fi = F % NF;
    int row = rowBase + fi * 16 + (lane & 15);
    row = min(row, M - 1);        // clamp: OOB rows feed only masked outputs
    srcOff[i] = (size_t)row * K + ks * 32 + ((lane >> 4) << 3);
  }

#define STAGE(b, t)                                                        \
  {                                                                        \
    _Pragma("unroll") for (int i = 0; i < FPW; i++)                        \
        gload_lds16(A + srcOff[i] + (size_t)(t) * 64,                      \
                    Ah[b] + (w * FPW + i) * 512);                          \
  }

  const int NT = K >> 6;
  STAGE(0, 0)
  __syncthreads();
  int cur = 0;
  for (int t = 0; t < NT; t++) {
    if (t + 1 < NT) {
      if (cur) STAGE(0, t + 1) else STAGE(1, t + 1)
    }
#pragma unroll
    for (int ks = 0; ks < 2; ks++) {
      int kidx = t * 64 + ks * 32 + kfrag;
      f16x8 bh0 = *(const f16x8*)(BT + (size_t)c0 * K + kidx);
      f16x8 bh1 = *(const f16x8*)(BT + (size_t)(c0 + 16) * K + kidx);
#pragma unroll
      for (int fi = 0; fi < NF; fi++) {
        f16x8 ah = *(const f16x8*)(Ah[cur] + (ks * NF + fi) * 512 + lane * 8);
        acc[fi][0] = __builtin_amdgcn_mfma_f32_16x16x32_f16(ah, bh0, acc[fi][0], 0, 0, 0);
        acc[fi][1] = __builtin_amdgcn_mfma_f32_16x16x32_f16(ah, bh1, acc[fi][1], 0, 0, 0);
      }
    }
    __syncthreads();  // drains prefetch of t+1; protects WAR on Ah[cur]
    cur ^= 1;
  }
#undef STAGE

  // epilogue
  const float bias0 = bias[c0], bias1 = bias[c0 + 16];
  float s1[2] = {0.f, 0.f}, s2[2] = {0.f, 0.f};
  const int rbase = rowBase + (lane >> 4) * 4;
#pragma unroll
  for (int fi = 0; fi < NF; fi++) {
#pragma unroll
    for (int j = 0; j < 4; j++) {
      int row = rbase + fi * 16 + j;
      float v0 = acc[fi][0][j] + bias0;
      float v1 = acc[fi][1][j] + bias1;
      if (doRelu) { v0 = fmaxf(v0, 0.f); v1 = fmaxf(v1, 0.f); }
      if (row < M) {
        Ch[(size_t)row * N + c0] = (_Float16)v0;
        Ch[(size_t)row * N + c0 + 16] = (_Float16)v1;
        s1[0] += v0; s2[0] += v0 * v0;
        s1[1] += v1; s2[1] += v1 * v1;
      }
    }
  }
  if (stats) {
#pragma unroll
    for (int off = 16; off < 64; off <<= 1) {
      s1[0] += __shfl_xor(s1[0], off);
      s2[0] += __shfl_xor(s2[0], off);
      s1[1] += __shfl_xor(s1[1], off);
      s2[1] += __shfl_xor(s2[1], off);
    }
    if (lane < 16) {
      atomicAdd(&stats[c0], s1[0]);
      atomicAdd(&stats[N + c0], s2[0]);
      atomicAdd(&stats[c0 + 16], s1[1]);
      atomicAdd(&stats[N + c0 + 16], s2[1]);
    }
  }
}

// ====== fused BN(fold from raw sums)+ReLU+segment-mean pool (layer 3, D=512) ======
__global__ __launch_bounds__(256) void bn_pool_kernel(
    const _Float16* __restrict__ h, const float* __restrict__ stats,
    const float* __restrict__ gamma, const float* __restrict__ beta,
    const int* __restrict__ batch, float* __restrict__ pooled, int N, float invN) {
  const int g = blockIdx.x >> 3;
  const int s = blockIdx.x & 7;
  __shared__ int s_lo, s_hi;
  if (threadIdx.x == 0) {
    int lo = 0, hi = N;
    while (lo < hi) { int m = (lo + hi) >> 1; if (batch[m] < g) lo = m + 1; else hi = m; }
    s_lo = lo;
    lo = 0; hi = N;
    while (lo < hi) { int m = (lo + hi) >> 1; if (batch[m] < g + 1) lo = m + 1; else hi = m; }
    s_hi = lo;
  }
  __syncthreads();
  const int lo = s_lo, hi = s_hi, len = hi - lo;
  if (len == 0) return;
  const int per = (len + 7) >> 3;
  const int rs = lo + s * per;
  const int re = min(rs + per, hi);
  if (rs >= re) return;
  const int t = threadIdx.x;
  float scv[2], shv[2];
#pragma unroll
  for (int j = 0; j < 2; j++) {
    int c = 2 * t + j;
    float mean = stats[c] * invN;
    float var = stats[512 + c] * invN - mean * mean;
    scv[j] = rsqrtf(var + 1e-5f) * gamma[c];
    shv[j] = beta[c] - mean * scv[j];
  }
  float ax = 0.f, ay = 0.f;
  for (int r = rs; r < re; r++) {
    f16x2 v = *(const f16x2*)(h + (size_t)r * 512 + 2 * t);
    ax += fmaxf((float)v[0] * scv[0] + shv[0], 0.f);
    ay += fmaxf((float)v[1] * scv[1] + shv[1], 0.f);
  }
  float inv = 1.f / (float)len;
  atomicAdd(&pooled[g * 512 + 2 * t], ax * inv);
  atomicAdd(&pooled[g * 512 + 2 * t + 1], ay * inv);
}

// ================= final projection =================
__global__ __launch_bounds__(64) void out_kernel(const float* __restrict__ pooled,
                                                 const float* __restrict__ wo,
                                                 const float* __restrict__ bo,
                                                 float* __restrict__ out) {
  int g = blockIdx.x, o = threadIdx.x;
  float acc = bo[o];
  for (int c = 0; c < 512; c++) acc += pooled[g * 512 + c] * wo[c * 64 + o];
  out[g * 64 + o] = fmaxf(acc, 0.f);
}

extern "C" void kernel_launch(void* const* d_in, const int* in_sizes, int n_in,
                              void* d_out, int out_size, void* d_ws, size_t ws_size,
                              hipStream_t stream) {
  const float* x0 = (const float*)d_in[0];
  const int* ei = (const int*)d_in[1];
  const int* batch = (const int*)d_in[2];
  const int N = in_sizes[0] / 128;
  const int E = in_sizes[1] / 2;
  const int* src = ei;
  const int* dst = ei + E;
  const float* W[3][6];
  for (int li = 0; li < 3; li++)
    for (int k = 0; k < 6; k++) W[li][k] = (const float*)d_in[3 + li * 6 + k];
  const float* wo = (const float*)d_in[21];
  const float* bo = (const float*)d_in[22];
  float* out = (float*)d_out;

  // workspace layout
  float* stats3 = (float*)d_ws;              // 3*1024
  float* pooled = stats3 + 3 * 1024;         // 64*512
  int* deg = (int*)(pooled + 64 * 512);      // N
  int* rowstart = deg + N;                   // N+1
  int* cursor = rowstart + N + 1;            // N
  int* nbr = cursor + N;                     // E
  uintptr_t wp = (uintptr_t)(nbr + E);
  wp = (wp + 15) & ~(uintptr_t)15;
  _Float16* aggh = (_Float16*)wp;            // N*256 f16
  _Float16* h1h = aggh + (size_t)N * 256;    // N*512 f16
  _Float16* h2h = h1h + (size_t)N * 512;     // N*512 f16
  _Float16* x0h = h2h + (size_t)N * 512;     // N*128 f16
  _Float16* wbuf = x0h + (size_t)N * 128;

  const int dins[3] = {128, 128, 256};
  const int douts[3] = {128, 256, 512};

  _Float16* WT[3][2];
  {
    _Float16* p = wbuf;
    for (int li = 0; li < 3; li++) {
      WT[li][0] = p; p += (size_t)dins[li] * douts[li];
      WT[li][1] = p; p += (size_t)douts[li] * douts[li];
    }
  }
  // batched weight prep (1 launch)
  {
    WAll wa;
    int maxTotal = 0;
    for (int li = 0; li < 3; li++) {
      int e1 = dins[li] * douts[li];
      int e2 = douts[li] * douts[li];
      wa.s[li * 2 + 0] = WSeg{W[li][0], WT[li][0], dins[li], douts[li], e1};
      wa.s[li * 2 + 1] = WSeg{W[li][2], WT[li][1], douts[li], douts[li], e2};
      maxTotal = max(maxTotal, max(e1, e2));
    }
    dim3 g((maxTotal + 255) / 256, 6);
    wprep_all_kernel<<<g, 256, 0, stream>>>(wa);
  }

  // x0 -> fp16, fused with zeroing deg + stats/pooled
  {
    int n4 = N * 32;
    int zn = 3 * 1024 + 64 * 512;
    xprep_kernel<<<(n4 + 255) / 256, 256, 0, stream>>>(
        (const float4*)x0, (f16x4*)x0h, n4, deg, N, stats3, zn);
  }

  // CSR build
  hist_kernel<<<(E + 255) / 256, 256, 0, stream>>>(dst, deg, E);
  scan_kernel<<<1, 1024, 0, stream>>>(deg, rowstart, cursor, N);
  fill_kernel<<<(E + 255) / 256, 256, 0, stream>>>(src, dst, cursor, nbr, E);

  const int mb32 = (N + 31) / 32;
  const int mb32_8 = ((mb32 + 7) / 8) * 8;
  const int gblocks = (N + 3) / 4;
  const float invN = 1.0f / N;

  for (int li = 0; li < 3; li++) {
    int Din = dins[li], Dout = douts[li];
    float* stats = stats3 + li * 1024;
    if (li == 0)
      gather_agg_kernel<2, false><<<gblocks, 256, 0, stream>>>(
          x0h, rowstart, nbr, nullptr, nullptr, nullptr, aggh, N, invN);
    else if (li == 1)
      gather_agg_kernel<2, true><<<gblocks, 256, 0, stream>>>(
          h2h, rowstart, nbr, stats3 + 0 * 1024, W[0][4], W[0][5], aggh, N, invN);
    else
      gather_agg_kernel<4, true><<<gblocks, 256, 0, stream>>>(
          h2h, rowstart, nbr, stats3 + 1 * 1024, W[1][4], W[1][5], aggh, N, invN);

    int cbShift = (Dout == 128) ? 0 : (Dout == 256) ? 1 : 2;
    int nblocks = mb32_8 << cbShift;
    gemm_mfma_kernel<32><<<nblocks, 256, 0, stream>>>(aggh, WT[li][0], W[li][1], h1h,
                                                      N, Din, Dout, mb32, cbShift, 1, nullptr);
    gemm_mfma_kernel<32><<<nblocks, 256, 0, stream>>>(h1h, WT[li][1], W[li][3], h2h,
                                                      N, Dout, Dout, mb32, cbShift, 0, stats);
    if (li == 2) {
      bn_pool_kernel<<<64 * 8, 256, 0, stream>>>(
          h2h, stats3 + 2 * 1024, W[2][4], W[2][5], batch, pooled, N, invN);
    }
  }
  out_kernel<<<64, 64, 0, stream>>>(pooled, wo, bo, out);
}

// Round 22
// 290.054 us; speedup vs baseline: 1.1128x; 1.1128x over previous
//
#include <hip/hip_runtime.h>

typedef float f32x4 __attribute__((ext_vector_type(4)));
typedef _Float16 f16x2 __attribute__((ext_vector_type(2)));
typedef _Float16 f16x4 __attribute__((ext_vector_type(4)));
typedef _Float16 f16x8 __attribute__((ext_vector_type(8)));

// async global->LDS, 16B per lane; LDS dest = wave-uniform base + lane*16B
__device__ __forceinline__ void gload_lds16(const _Float16* g, _Float16* l) {
  __builtin_amdgcn_global_load_lds(
      (const __attribute__((address_space(1))) unsigned int*)g,
      (__attribute__((address_space(3))) unsigned int*)l, 16, 0, 0);
}

// ================= CSR build =================
__global__ __launch_bounds__(256) void hist_kernel(const int* __restrict__ dst,
                                                   int* __restrict__ deg, int E) {
  int e = blockIdx.x * 256 + threadIdx.x;
  if (e < E) atomicAdd(&deg[dst[e]], 1);
}

__global__ __launch_bounds__(1024) void scan_kernel(const int* __restrict__ deg,
                                                    int* __restrict__ rowstart,
                                                    int* __restrict__ cursor, int N) {
  __shared__ int sums[1024];
  const int t = threadIdx.x;
  const int CH = (N + 1023) >> 10;
  int local[32];
  int base = t * CH;
  int s = 0;
  for (int i = 0; i < CH; i++) {
    int idx = base + i;
    int v = (idx < N) ? deg[idx] : 0;
    local[i] = s;
    s += v;
  }
  sums[t] = s;
  __syncthreads();
  for (int off = 1; off < 1024; off <<= 1) {
    int add = (t >= off) ? sums[t - off] : 0;
    __syncthreads();
    sums[t] += add;
    __syncthreads();
  }
  int prefix = sums[t] - s;
  for (int i = 0; i < CH; i++) {
    int idx = base + i;
    if (idx < N) {
      int v = prefix + local[i];
      rowstart[idx] = v;
      cursor[idx] = v;
    }
  }
  if (t == 1023) rowstart[N] = sums[1023];
}

__global__ __launch_bounds__(256) void fill_kernel(const int* __restrict__ src,
                                                   const int* __restrict__ dst,
                                                   int* __restrict__ cursor,
                                                   int* __restrict__ nbr, int E) {
  int e = blockIdx.x * 256 + threadIdx.x;
  if (e >= E) return;
  int pos = atomicAdd(&cursor[dst[e]], 1);
  nbr[pos] = src[e];
}

// ========= x0 fp32 -> fp16, fused with zeroing deg + stats/pooled =========
__global__ __launch_bounds__(256) void xprep_kernel(const float4* __restrict__ in,
                                                    f16x4* __restrict__ out, int n4,
                                                    int* __restrict__ deg, int N,
                                                    float* __restrict__ zbuf, int zn) {
  int i = blockIdx.x * 256 + threadIdx.x;
  if (i < N) deg[i] = 0;
  if (i < zn) zbuf[i] = 0.f;
  if (i >= n4) return;
  float4 v = in[i];
  f16x4 h;
  h[0] = (_Float16)v.x; h[1] = (_Float16)v.y;
  h[2] = (_Float16)v.z; h[3] = (_Float16)v.w;
  out[i] = h;
}

// ====== gather over fp16 rows; BN fold (from raw sums) + ReLU fused; fp16 output ======
template <int C, bool BNIN>
__global__ __launch_bounds__(256) void gather_agg_kernel(
    const _Float16* __restrict__ x, const int* __restrict__ rowstart,
    const int* __restrict__ nbr, const float* __restrict__ stats,
    const float* __restrict__ gamma, const float* __restrict__ beta,
    _Float16* __restrict__ agg, int N, float invN) {
  constexpr int Din = 64 * C;
  const int wave = threadIdx.x >> 6;
  const int lane = threadIdx.x & 63;
  const int node = blockIdx.x * 4 + wave;
  if (node >= N) return;

  float sc[C], sh[C];
  if constexpr (BNIN) {
#pragma unroll
    for (int j = 0; j < C; j++) {
      int c = lane * C + j;
      float mean = stats[c] * invN;
      float var = stats[Din + c] * invN - mean * mean;
      sc[j] = rsqrtf(var + 1e-5f) * gamma[c];
      sh[j] = beta[c] - mean * sc[j];
    }
  }

#define LOADROW(dstv, rowidx)                                              \
  {                                                                        \
    const _Float16* _p = x + (size_t)(rowidx)*Din + lane * C;              \
    if constexpr (C == 2) {                                                \
      f16x2 _t = *(const f16x2*)_p;                                        \
      dstv[0] = (float)_t[0]; dstv[1] = (float)_t[1];                      \
    } else {                                                               \
      f16x4 _t = *(const f16x4*)_p;                                        \
      dstv[0] = (float)_t[0]; dstv[1] = (float)_t[1];                      \
      dstv[2] = (float)_t[2]; dstv[3] = (float)_t[3];                      \
    }                                                                      \
  }
#define ACCUM(vv)                                                          \
  _Pragma("unroll") for (int j = 0; j < C; j++)                            \
      acc[j] += BNIN ? fmaxf(vv[j] * sc[j] + sh[j], 0.f) : vv[j];

  float acc[C];
  {
    float v[C];
    LOADROW(v, node)
#pragma unroll
    for (int j = 0; j < C; j++)
      acc[j] = BNIN ? fmaxf(v[j] * sc[j] + sh[j], 0.f) : v[j];
  }
  const int rs = rowstart[node], re = rowstart[node + 1];
  int e = rs;
  for (; e + 3 < re; e += 4) {
    int s0 = nbr[e], s1 = nbr[e + 1], s2 = nbr[e + 2], s3 = nbr[e + 3];
    float v0[C], v1[C], v2[C], v3[C];
    LOADROW(v0, s0)
    LOADROW(v1, s1)
    LOADROW(v2, s2)
    LOADROW(v3, s3)
    ACCUM(v0) ACCUM(v1) ACCUM(v2) ACCUM(v3)
  }
  for (; e + 1 < re; e += 2) {
    int s0 = nbr[e], s1 = nbr[e + 1];
    float v0[C], v1[C];
    LOADROW(v0, s0)
    LOADROW(v1, s1)
    ACCUM(v0) ACCUM(v1)
  }
  if (e < re) {
    int s0 = nbr[e];
    float v0[C];
    LOADROW(v0, s0)
    ACCUM(v0)
  }
#undef ACCUM
#undef LOADROW

  _Float16* o = agg + (size_t)node * Din + lane * C;
  if constexpr (C == 2) {
    f16x2 r; r[0] = (_Float16)acc[0]; r[1] = (_Float16)acc[1];
    *(f16x2*)o = r;
  } else {
    f16x4 r;
    r[0] = (_Float16)acc[0]; r[1] = (_Float16)acc[1];
    r[2] = (_Float16)acc[2]; r[3] = (_Float16)acc[3];
    *(f16x4*)o = r;
  }
}

// ================= batched weight prep: W[K][N] fp32 -> WT [N][K] fp16 =================
struct WSeg {
  const float* W;
  _Float16* TH;
  int K, N, total;
};
struct WAll { WSeg s[6]; };

__global__ __launch_bounds__(256) void wprep_all_kernel(WAll a) {
  WSeg sg = a.s[blockIdx.y];
  int idx = blockIdx.x * 256 + threadIdx.x;
  if (idx >= sg.total) return;
  int k = idx / sg.N, n = idx - k * sg.N;
  sg.TH[(size_t)n * sg.K + k] = (_Float16)sg.W[idx];
}

// ===== MFMA GEMM: C = A[MxK] @ B[KxN] + bias, all-FP16 (fp32 accumulate) =====
// RT rows x 128 cols per block, 4 waves, BK=64; XCD swizzle.
// T4 pipeline: 3 LDS buffers, prefetch depth 2 via global_load_lds; per step the B-loads
// are issued BEFORE the stage so the compiler's B-wait retires the OLDER stage (FIFO)
// while the newest stage stays in flight across a RAW s_barrier (no vmcnt(0) drain).
// Prologue wait is vmcnt(FPW): retires stage(0) exactly, leaves stage(1) in flight.
template <int RT>
__global__ __launch_bounds__(256, 4) void gemm_mfma_kernel(
    const _Float16* __restrict__ A, const _Float16* __restrict__ BT,
    const float* __restrict__ bias, _Float16* __restrict__ Ch,
    int M, int K, int N, int mblocks, int cbShift,
    int doRelu, float* __restrict__ stats) {
  constexpr int NF = RT / 16;   // row frags per 32-K half
  constexpr int NFT = 2 * NF;   // frags per 64-K step
  constexpr int FPW = NFT / 4;  // frags staged per wave (2 for RT=64, 1 for RT=32)
  __shared__ _Float16 Ah[3][NFT * 512];
  const int bid = blockIdx.x;
  const int xcd = bid & 7;
  const int q = bid >> 3;
  const int r = ((q >> cbShift) << 3) + xcd;
  const int cb = q & ((1 << cbShift) - 1);
  if (r >= mblocks) return;

  const int tid = threadIdx.x;
  const int lane = tid & 63;
  const int w = tid >> 6;
  const int rowBase = r * RT;
  const int colBase = cb * 128 + w * 32;

  f32x4 acc[NF][2] = {};
  const int c0 = colBase + (lane & 15);
  const int kfrag = (lane >> 4) * 8;

  // pre-swizzled per-lane global source offsets (one per staged fragment)
  size_t srcOff[FPW];
#pragma unroll
  for (int i = 0; i < FPW; i++) {
    int F = w * FPW + i;          // fragment index: F = ks*NF + fi
    int ks = F / NF, fi = F % NF;
    int row = rowBase + fi * 16 + (lane & 15);
    row = min(row, M - 1);        // clamp: OOB rows feed only masked outputs
    srcOff[i] = (size_t)row * K + ks * 32 + ((lane >> 4) << 3);
  }

#define STAGE(b, t)                                                        \
  {                                                                        \
    _Pragma("unroll") for (int i = 0; i < FPW; i++)                        \
        gload_lds16(A + srcOff[i] + (size_t)(t) * 64,                      \
                    &Ah[b][(w * FPW + i) * 512]);                          \
  }

  const int NT = K >> 6;
  STAGE(0, 0)
  if (NT > 1) {
    STAGE(1, 1)
    // retire stage(0) exactly; stage(1) (FPW loads) stays in flight
    if constexpr (FPW == 2)
      asm volatile("s_waitcnt vmcnt(2)" ::: "memory");
    else
      asm volatile("s_waitcnt vmcnt(1)" ::: "memory");
  } else {
    asm volatile("s_waitcnt vmcnt(0)" ::: "memory");
  }
  __builtin_amdgcn_s_barrier();
  __builtin_amdgcn_sched_barrier(0);

  int cur = 0;
  for (int t = 0; t < NT; t++) {
    // 1) B fragments for this step (issued FIRST -> older than the stage below)
    f16x8 bh[2][2];
#pragma unroll
    for (int ks = 0; ks < 2; ks++) {
      int kidx = t * 64 + ks * 32 + kfrag;
      bh[ks][0] = *(const f16x8*)(BT + (size_t)c0 * K + kidx);
      bh[ks][1] = *(const f16x8*)(BT + (size_t)(c0 + 16) * K + kidx);
    }
    __builtin_amdgcn_sched_barrier(0);
    // 2) prefetch tile t+2 (newest in vmcnt FIFO; survives the B-wait and the barrier)
    if (t + 2 < NT) {
      int b2 = (cur >= 1) ? cur - 1 : 2;  // (t+2)%3
      STAGE(b2, t + 2)
    }
    __builtin_amdgcn_sched_barrier(0);
    // 3) compute from Ah[cur]; compiler's wait for bh retires stage(t+1) (FIFO), not t+2
#pragma unroll
    for (int ks = 0; ks < 2; ks++) {
#pragma unroll
      for (int fi = 0; fi < NF; fi++) {
        f16x8 ah = *(const f16x8*)(&Ah[cur][(ks * NF + fi) * 512 + lane * 8]);
        acc[fi][0] = __builtin_amdgcn_mfma_f32_16x16x32_f16(ah, bh[ks][0], acc[fi][0], 0, 0, 0);
        acc[fi][1] = __builtin_amdgcn_mfma_f32_16x16x32_f16(ah, bh[ks][1], acc[fi][1], 0, 0, 0);
      }
    }
    if (t + 1 < NT) {
      __builtin_amdgcn_s_barrier();       // raw barrier: no vmcnt(0) drain
      __builtin_amdgcn_sched_barrier(0);
    }
    cur = (cur == 2) ? 0 : cur + 1;
  }
#undef STAGE

  // epilogue
  const float bias0 = bias[c0], bias1 = bias[c0 + 16];
  float s1[2] = {0.f, 0.f}, s2[2] = {0.f, 0.f};
  const int rbase = rowBase + (lane >> 4) * 4;
#pragma unroll
  for (int fi = 0; fi < NF; fi++) {
#pragma unroll
    for (int j = 0; j < 4; j++) {
      int row = rbase + fi * 16 + j;
      float v0 = acc[fi][0][j] + bias0;
      float v1 = acc[fi][1][j] + bias1;
      if (doRelu) { v0 = fmaxf(v0, 0.f); v1 = fmaxf(v1, 0.f); }
      if (row < M) {
        Ch[(size_t)row * N + c0] = (_Float16)v0;
        Ch[(size_t)row * N + c0 + 16] = (_Float16)v1;
        s1[0] += v0; s2[0] += v0 * v0;
        s1[1] += v1; s2[1] += v1 * v1;
      }
    }
  }
  if (stats) {
#pragma unroll
    for (int off = 16; off < 64; off <<= 1) {
      s1[0] += __shfl_xor(s1[0], off);
      s2[0] += __shfl_xor(s2[0], off);
      s1[1] += __shfl_xor(s1[1], off);
      s2[1] += __shfl_xor(s2[1], off);
    }
    if (lane < 16) {
      atomicAdd(&stats[c0], s1[0]);
      atomicAdd(&stats[N + c0], s2[0]);
      atomicAdd(&stats[c0 + 16], s1[1]);
      atomicAdd(&stats[N + c0 + 16], s2[1]);
    }
  }
}

// ====== fused BN(fold from raw sums)+ReLU+segment-mean pool (layer 3, D=512) ======
__global__ __launch_bounds__(256) void bn_pool_kernel(
    const _Float16* __restrict__ h, const float* __restrict__ stats,
    const float* __restrict__ gamma, const float* __restrict__ beta,
    const int* __restrict__ batch, float* __restrict__ pooled, int N, float invN) {
  const int g = blockIdx.x >> 3;
  const int s = blockIdx.x & 7;
  __shared__ int s_lo, s_hi;
  if (threadIdx.x == 0) {
    int lo = 0, hi = N;
    while (lo < hi) { int m = (lo + hi) >> 1; if (batch[m] < g) lo = m + 1; else hi = m; }
    s_lo = lo;
    lo = 0; hi = N;
    while (lo < hi) { int m = (lo + hi) >> 1; if (batch[m] < g + 1) lo = m + 1; else hi = m; }
    s_hi = lo;
  }
  __syncthreads();
  const int lo = s_lo, hi = s_hi, len = hi - lo;
  if (len == 0) return;
  const int per = (len + 7) >> 3;
  const int rs = lo + s * per;
  const int re = min(rs + per, hi);
  if (rs >= re) return;
  const int t = threadIdx.x;
  float scv[2], shv[2];
#pragma unroll
  for (int j = 0; j < 2; j++) {
    int c = 2 * t + j;
    float mean = stats[c] * invN;
    float var = stats[512 + c] * invN - mean * mean;
    scv[j] = rsqrtf(var + 1e-5f) * gamma[c];
    shv[j] = beta[c] - mean * scv[j];
  }
  float ax = 0.f, ay = 0.f;
  for (int r = rs; r < re; r++) {
    f16x2 v = *(const f16x2*)(h + (size_t)r * 512 + 2 * t);
    ax += fmaxf((float)v[0] * scv[0] + shv[0], 0.f);
    ay += fmaxf((float)v[1] * scv[1] + shv[1], 0.f);
  }
  float inv = 1.f / (float)len;
  atomicAdd(&pooled[g * 512 + 2 * t], ax * inv);
  atomicAdd(&pooled[g * 512 + 2 * t + 1], ay * inv);
}

// ================= final projection =================
__global__ __launch_bounds__(64) void out_kernel(const float* __restrict__ pooled,
                                                 const float* __restrict__ wo,
                                                 const float* __restrict__ bo,
                                                 float* __restrict__ out) {
  int g = blockIdx.x, o = threadIdx.x;
  float acc = bo[o];
  for (int c = 0; c < 512; c++) acc += pooled[g * 512 + c] * wo[c * 64 + o];
  out[g * 64 + o] = fmaxf(acc, 0.f);
}

extern "C" void kernel_launch(void* const* d_in, const int* in_sizes, int n_in,
                              void* d_out, int out_size, void* d_ws, size_t ws_size,
                              hipStream_t stream) {
  const float* x0 = (const float*)d_in[0];
  const int* ei = (const int*)d_in[1];
  const int* batch = (const int*)d_in[2];
  const int N = in_sizes[0] / 128;
  const int E = in_sizes[1] / 2;
  const int* src = ei;
  const int* dst = ei + E;
  const float* W[3][6];
  for (int li = 0; li < 3; li++)
    for (int k = 0; k < 6; k++) W[li][k] = (const float*)d_in[3 + li * 6 + k];
  const float* wo = (const float*)d_in[21];
  const float* bo = (const float*)d_in[22];
  float* out = (float*)d_out;

  // workspace layout
  float* stats3 = (float*)d_ws;              // 3*1024
  float* pooled = stats3 + 3 * 1024;         // 64*512
  int* deg = (int*)(pooled + 64 * 512);      // N
  int* rowstart = deg + N;                   // N+1
  int* cursor = rowstart + N + 1;            // N
  int* nbr = cursor + N;                     // E
  uintptr_t wp = (uintptr_t)(nbr + E);
  wp = (wp + 15) & ~(uintptr_t)15;
  _Float16* aggh = (_Float16*)wp;            // N*256 f16
  _Float16* h1h = aggh + (size_t)N * 256;    // N*512 f16
  _Float16* h2h = h1h + (size_t)N * 512;     // N*512 f16
  _Float16* x0h = h2h + (size_t)N * 512;     // N*128 f16
  _Float16* wbuf = x0h + (size_t)N * 128;

  const int dins[3] = {128, 128, 256};
  const int douts[3] = {128, 256, 512};

  _Float16* WT[3][2];
  {
    _Float16* p = wbuf;
    for (int li = 0; li < 3; li++) {
      WT[li][0] = p; p += (size_t)dins[li] * douts[li];
      WT[li][1] = p; p += (size_t)douts[li] * douts[li];
    }
  }
  // batched weight prep (1 launch)
  {
    WAll wa;
    int maxTotal = 0;
    for (int li = 0; li < 3; li++) {
      int e1 = dins[li] * douts[li];
      int e2 = douts[li] * douts[li];
      wa.s[li * 2 + 0] = WSeg{W[li][0], WT[li][0], dins[li], douts[li], e1};
      wa.s[li * 2 + 1] = WSeg{W[li][2], WT[li][1], douts[li], douts[li], e2};
      maxTotal = max(maxTotal, max(e1, e2));
    }
    dim3 g((maxTotal + 255) / 256, 6);
    wprep_all_kernel<<<g, 256, 0, stream>>>(wa);
  }

  // x0 -> fp16, fused with zeroing deg + stats/pooled
  {
    int n4 = N * 32;
    int zn = 3 * 1024 + 64 * 512;
    xprep_kernel<<<(n4 + 255) / 256, 256, 0, stream>>>(
        (const float4*)x0, (f16x4*)x0h, n4, deg, N, stats3, zn);
  }

  // CSR build
  hist_kernel<<<(E + 255) / 256, 256, 0, stream>>>(dst, deg, E);
  scan_kernel<<<1, 1024, 0, stream>>>(deg, rowstart, cursor, N);
  fill_kernel<<<(E + 255) / 256, 256, 0, stream>>>(src, dst, cursor, nbr, E);

  const int mb64 = (N + 63) / 64;
  const int mb64_8 = ((mb64 + 7) / 8) * 8;
  const int mb32 = (N + 31) / 32;
  const int mb32_8 = ((mb32 + 7) / 8) * 8;
  const int gblocks = (N + 3) / 4;
  const float invN = 1.0f / N;

  for (int li = 0; li < 3; li++) {
    int Din = dins[li], Dout = douts[li];
    float* stats = stats3 + li * 1024;
    if (li == 0)
      gather_agg_kernel<2, false><<<gblocks, 256, 0, stream>>>(
          x0h, rowstart, nbr, nullptr, nullptr, nullptr, aggh, N, invN);
    else if (li == 1)
      gather_agg_kernel<2, true><<<gblocks, 256, 0, stream>>>(
          h2h, rowstart, nbr, stats3 + 0 * 1024, W[0][4], W[0][5], aggh, N, invN);
    else
      gather_agg_kernel<4, true><<<gblocks, 256, 0, stream>>>(
          h2h, rowstart, nbr, stats3 + 1 * 1024, W[1][4], W[1][5], aggh, N, invN);

    if (Dout == 128) {
      gemm_mfma_kernel<32><<<mb32_8, 256, 0, stream>>>(aggh, WT[li][0], W[li][1], h1h,
                                                       N, Din, Dout, mb32, 0, 1, nullptr);
      gemm_mfma_kernel<32><<<mb32_8, 256, 0, stream>>>(h1h, WT[li][1], W[li][3], h2h,
                                                       N, Dout, Dout, mb32, 0, 0, stats);
    } else {
      int cbShift = (Dout == 256) ? 1 : 2;
      int nblocks = mb64_8 << cbShift;
      gemm_mfma_kernel<64><<<nblocks, 256, 0, stream>>>(aggh, WT[li][0], W[li][1], h1h,
                                                        N, Din, Dout, mb64, cbShift, 1, nullptr);
      gemm_mfma_kernel<64><<<nblocks, 256, 0, stream>>>(h1h, WT[li][1], W[li][3], h2h,
                                                        N, Dout, Dout, mb64, cbShift, 0, stats);
    }
    if (li == 2) {
      bn_pool_kernel<<<64 * 8, 256, 0, stream>>>(
          h2h, stats3 + 2 * 1024, W[2][4], W[2][5], batch, pooled, N, invN);
    }
  }
  out_kernel<<<64, 64, 0, stream>>>(pooled, wo, bo, out);
}

// Round 23
// 266.581 us; speedup vs baseline: 1.2108x; 1.0881x over previous
//
#include <hip/hip_runtime.h>

typedef float f32x4 __attribute__((ext_vector_type(4)));
typedef _Float16 f16x2 __attribute__((ext_vector_type(2)));
typedef _Float16 f16x4 __attribute__((ext_vector_type(4)));
typedef _Float16 f16x8 __attribute__((ext_vector_type(8)));

// async global->LDS, 16B per lane; LDS dest = wave-uniform base + lane*16B
__device__ __forceinline__ void gload_lds16(const _Float16* g, _Float16* l) {
  __builtin_amdgcn_global_load_lds(
      (const __attribute__((address_space(1))) unsigned int*)g,
      (__attribute__((address_space(3))) unsigned int*)l, 16, 0, 0);
}

// ================= CSR build =================
__global__ __launch_bounds__(256) void hist_kernel(const int* __restrict__ dst,
                                                   int* __restrict__ deg, int E) {
  int e = blockIdx.x * 256 + threadIdx.x;
  if (e < E) atomicAdd(&deg[dst[e]], 1);
}

__global__ __launch_bounds__(1024) void scan_kernel(const int* __restrict__ deg,
                                                    int* __restrict__ rowstart,
                                                    int* __restrict__ cursor, int N) {
  __shared__ int sums[1024];
  const int t = threadIdx.x;
  const int CH = (N + 1023) >> 10;
  int local[32];
  int base = t * CH;
  int s = 0;
  for (int i = 0; i < CH; i++) {
    int idx = base + i;
    int v = (idx < N) ? deg[idx] : 0;
    local[i] = s;
    s += v;
  }
  sums[t] = s;
  __syncthreads();
  for (int off = 1; off < 1024; off <<= 1) {
    int add = (t >= off) ? sums[t - off] : 0;
    __syncthreads();
    sums[t] += add;
    __syncthreads();
  }
  int prefix = sums[t] - s;
  for (int i = 0; i < CH; i++) {
    int idx = base + i;
    if (idx < N) {
      int v = prefix + local[i];
      rowstart[idx] = v;
      cursor[idx] = v;
    }
  }
  if (t == 1023) rowstart[N] = sums[1023];
}

__global__ __launch_bounds__(256) void fill_kernel(const int* __restrict__ src,
                                                   const int* __restrict__ dst,
                                                   int* __restrict__ cursor,
                                                   int* __restrict__ nbr, int E) {
  int e = blockIdx.x * 256 + threadIdx.x;
  if (e >= E) return;
  int pos = atomicAdd(&cursor[dst[e]], 1);
  nbr[pos] = src[e];
}

// ========= x0 fp32 -> fp16, fused with zeroing deg + stats/pooled =========
__global__ __launch_bounds__(256) void xprep_kernel(const float4* __restrict__ in,
                                                    f16x4* __restrict__ out, int n4,
                                                    int* __restrict__ deg, int N,
                                                    float* __restrict__ zbuf, int zn) {
  int i = blockIdx.x * 256 + threadIdx.x;
  if (i < N) deg[i] = 0;
  if (i < zn) zbuf[i] = 0.f;
  if (i >= n4) return;
  float4 v = in[i];
  f16x4 h;
  h[0] = (_Float16)v.x; h[1] = (_Float16)v.y;
  h[2] = (_Float16)v.z; h[3] = (_Float16)v.w;
  out[i] = h;
}

// ====== gather over fp16 rows; BN fold (from raw sums) + ReLU fused; fp16 output ======
template <int C, bool BNIN>
__global__ __launch_bounds__(256) void gather_agg_kernel(
    const _Float16* __restrict__ x, const int* __restrict__ rowstart,
    const int* __restrict__ nbr, const float* __restrict__ stats,
    const float* __restrict__ gamma, const float* __restrict__ beta,
    _Float16* __restrict__ agg, int N, float invN) {
  constexpr int Din = 64 * C;
  const int wave = threadIdx.x >> 6;
  const int lane = threadIdx.x & 63;
  const int node = blockIdx.x * 4 + wave;
  if (node >= N) return;

  float sc[C], sh[C];
  if constexpr (BNIN) {
#pragma unroll
    for (int j = 0; j < C; j++) {
      int c = lane * C + j;
      float mean = stats[c] * invN;
      float var = stats[Din + c] * invN - mean * mean;
      sc[j] = rsqrtf(var + 1e-5f) * gamma[c];
      sh[j] = beta[c] - mean * sc[j];
    }
  }

#define LOADROW(dstv, rowidx)                                              \
  {                                                                        \
    const _Float16* _p = x + (size_t)(rowidx)*Din + lane * C;              \
    if constexpr (C == 2) {                                                \
      f16x2 _t = *(const f16x2*)_p;                                        \
      dstv[0] = (float)_t[0]; dstv[1] = (float)_t[1];                      \
    } else {                                                               \
      f16x4 _t = *(const f16x4*)_p;                                        \
      dstv[0] = (float)_t[0]; dstv[1] = (float)_t[1];                      \
      dstv[2] = (float)_t[2]; dstv[3] = (float)_t[3];                      \
    }                                                                      \
  }
#define ACCUM(vv)                                                          \
  _Pragma("unroll") for (int j = 0; j < C; j++)                            \
      acc[j] += BNIN ? fmaxf(vv[j] * sc[j] + sh[j], 0.f) : vv[j];

  float acc[C];
  {
    float v[C];
    LOADROW(v, node)
#pragma unroll
    for (int j = 0; j < C; j++)
      acc[j] = BNIN ? fmaxf(v[j] * sc[j] + sh[j], 0.f) : v[j];
  }
  const int rs = rowstart[node], re = rowstart[node + 1];
  int e = rs;
  for (; e + 3 < re; e += 4) {
    int s0 = nbr[e], s1 = nbr[e + 1], s2 = nbr[e + 2], s3 = nbr[e + 3];
    float v0[C], v1[C], v2[C], v3[C];
    LOADROW(v0, s0)
    LOADROW(v1, s1)
    LOADROW(v2, s2)
    LOADROW(v3, s3)
    ACCUM(v0) ACCUM(v1) ACCUM(v2) ACCUM(v3)
  }
  for (; e + 1 < re; e += 2) {
    int s0 = nbr[e], s1 = nbr[e + 1];
    float v0[C], v1[C];
    LOADROW(v0, s0)
    LOADROW(v1, s1)
    ACCUM(v0) ACCUM(v1)
  }
  if (e < re) {
    int s0 = nbr[e];
    float v0[C];
    LOADROW(v0, s0)
    ACCUM(v0)
  }
#undef ACCUM
#undef LOADROW

  _Float16* o = agg + (size_t)node * Din + lane * C;
  if constexpr (C == 2) {
    f16x2 r; r[0] = (_Float16)acc[0]; r[1] = (_Float16)acc[1];
    *(f16x2*)o = r;
  } else {
    f16x4 r;
    r[0] = (_Float16)acc[0]; r[1] = (_Float16)acc[1];
    r[2] = (_Float16)acc[2]; r[3] = (_Float16)acc[3];
    *(f16x4*)o = r;
  }
}

// ====== batched weight prep: W[K][N] fp32 -> fragment-linear fp16 B-tables ======
// Fragment f=(n>>4)*(K/32)+(k>>5); within: slot=(n&15)|(((k>>3)&3)<<4), elem=k&7.
// A wave's B-fragment load is then ONE contiguous 1KB read (8 full 128B lines).
struct WSeg {
  const float* W;
  _Float16* TH;
  int K, N, total;
};
struct WAll { WSeg s[6]; };

__global__ __launch_bounds__(256) void wprep_all_kernel(WAll a) {
  WSeg sg = a.s[blockIdx.y];
  int idx = blockIdx.x * 256 + threadIdx.x;
  if (idx >= sg.total) return;
  int k = idx / sg.N, n = idx - k * sg.N;
  int KT = sg.K >> 5;
  int frag = (n >> 4) * KT + (k >> 5);
  int slot = (n & 15) | (((k >> 3) & 3) << 4);
  sg.TH[(size_t)frag * 512 + slot * 8 + (k & 7)] = (_Float16)sg.W[idx];
}

// ===== MFMA GEMM: C = A[MxK] @ B[KxN] + bias, all-FP16 (fp32 accumulate) =====
// RT rows x 128 cols per block, 4 waves, BK=64; XCD swizzle.
// A staged via global_load_lds (pre-swizzled per-lane sources), 3 buffers, prefetch
// depth 2, B issued before stage (FIFO keeps newest prefetch in flight), raw s_barrier.
// B-tables are fragment-linear: each B fragment is one contiguous 1KB wave load.
template <int RT>
__global__ __launch_bounds__(256, 4) void gemm_mfma_kernel(
    const _Float16* __restrict__ A, const _Float16* __restrict__ BT,
    const float* __restrict__ bias, _Float16* __restrict__ Ch,
    int M, int K, int N, int mblocks, int cbShift,
    int doRelu, float* __restrict__ stats) {
  constexpr int NF = RT / 16;   // row frags per 32-K half
  constexpr int NFT = 2 * NF;   // frags per 64-K step
  constexpr int FPW = NFT / 4;  // frags staged per wave (2 for RT=64, 1 for RT=32)
  __shared__ _Float16 Ah[3][NFT * 512];
  const int bid = blockIdx.x;
  const int xcd = bid & 7;
  const int q = bid >> 3;
  const int r = ((q >> cbShift) << 3) + xcd;
  const int cb = q & ((1 << cbShift) - 1);
  if (r >= mblocks) return;

  const int tid = threadIdx.x;
  const int lane = tid & 63;
  const int w = tid >> 6;
  const int rowBase = r * RT;
  const int colBase = cb * 128 + w * 32;
  const int KT = K >> 5;  // k-fragments per col-tile

  f32x4 acc[NF][2] = {};
  const int c0 = colBase + (lane & 15);
  // fragment-linear B bases for this wave's two col-tiles
  const size_t bBase0 = ((size_t)(colBase >> 4) * KT) * 512 + (size_t)lane * 8;
  const size_t bBase1 = bBase0 + (size_t)KT * 512;

  // pre-swizzled per-lane global source offsets for A staging
  size_t srcOff[FPW];
#pragma unroll
  for (int i = 0; i < FPW; i++) {
    int F = w * FPW + i;          // fragment index: F = ks*NF + fi
    int ks = F / NF, fi = F % NF;
    int row = rowBase + fi * 16 + (lane & 15);
    row = min(row, M - 1);        // clamp: OOB rows feed only masked outputs
    srcOff[i] = (size_t)row * K + ks * 32 + ((lane >> 4) << 3);
  }

#define STAGE(b, t)                                                        \
  {                                                                        \
    _Pragma("unroll") for (int i = 0; i < FPW; i++)                        \
        gload_lds16(A + srcOff[i] + (size_t)(t) * 64,                      \
                    &Ah[b][(w * FPW + i) * 512]);                          \
  }

  const int NT = K >> 6;
  STAGE(0, 0)
  if (NT > 1) {
    STAGE(1, 1)
    if constexpr (FPW == 2)
      asm volatile("s_waitcnt vmcnt(2)" ::: "memory");
    else
      asm volatile("s_waitcnt vmcnt(1)" ::: "memory");
  } else {
    asm volatile("s_waitcnt vmcnt(0)" ::: "memory");
  }
  __builtin_amdgcn_s_barrier();
  __builtin_amdgcn_sched_barrier(0);

  int cur = 0;
  for (int t = 0; t < NT; t++) {
    // 1) B fragments (contiguous 1KB wave loads), issued FIRST
    f16x8 bh[2][2];
#pragma unroll
    for (int ks = 0; ks < 2; ks++) {
      int kf = t * 2 + ks;
      bh[ks][0] = *(const f16x8*)(BT + bBase0 + (size_t)kf * 512);
      bh[ks][1] = *(const f16x8*)(BT + bBase1 + (size_t)kf * 512);
    }
    __builtin_amdgcn_sched_barrier(0);
    // 2) prefetch tile t+2 (newest in FIFO; survives B-wait and barrier)
    if (t + 2 < NT) {
      int b2 = (cur >= 1) ? cur - 1 : 2;  // (t+2)%3
      STAGE(b2, t + 2)
    }
    __builtin_amdgcn_sched_barrier(0);
    // 3) compute from Ah[cur]; B-wait retires stage(t+1) (FIFO), not t+2
#pragma unroll
    for (int ks = 0; ks < 2; ks++) {
#pragma unroll
      for (int fi = 0; fi < NF; fi++) {
        f16x8 ah = *(const f16x8*)(&Ah[cur][(ks * NF + fi) * 512 + lane * 8]);
        acc[fi][0] = __builtin_amdgcn_mfma_f32_16x16x32_f16(ah, bh[ks][0], acc[fi][0], 0, 0, 0);
        acc[fi][1] = __builtin_amdgcn_mfma_f32_16x16x32_f16(ah, bh[ks][1], acc[fi][1], 0, 0, 0);
      }
    }
    if (t + 1 < NT) {
      __builtin_amdgcn_s_barrier();       // raw barrier: no vmcnt(0) drain
      __builtin_amdgcn_sched_barrier(0);
    }
    cur = (cur == 2) ? 0 : cur + 1;
  }
#undef STAGE

  // epilogue
  const float bias0 = bias[c0], bias1 = bias[c0 + 16];
  float s1[2] = {0.f, 0.f}, s2[2] = {0.f, 0.f};
  const int rbase = rowBase + (lane >> 4) * 4;
#pragma unroll
  for (int fi = 0; fi < NF; fi++) {
#pragma unroll
    for (int j = 0; j < 4; j++) {
      int row = rbase + fi * 16 + j;
      float v0 = acc[fi][0][j] + bias0;
      float v1 = acc[fi][1][j] + bias1;
      if (doRelu) { v0 = fmaxf(v0, 0.f); v1 = fmaxf(v1, 0.f); }
      if (row < M) {
        Ch[(size_t)row * N + c0] = (_Float16)v0;
        Ch[(size_t)row * N + c0 + 16] = (_Float16)v1;
        s1[0] += v0; s2[0] += v0 * v0;
        s1[1] += v1; s2[1] += v1 * v1;
      }
    }
  }
  if (stats) {
#pragma unroll
    for (int off = 16; off < 64; off <<= 1) {
      s1[0] += __shfl_xor(s1[0], off);
      s2[0] += __shfl_xor(s2[0], off);
      s1[1] += __shfl_xor(s1[1], off);
      s2[1] += __shfl_xor(s2[1], off);
    }
    if (lane < 16) {
      atomicAdd(&stats[c0], s1[0]);
      atomicAdd(&stats[N + c0], s2[0]);
      atomicAdd(&stats[c0 + 16], s1[1]);
      atomicAdd(&stats[N + c0 + 16], s2[1]);
    }
  }
}

// ====== fused BN(fold from raw sums)+ReLU+segment-mean pool (layer 3, D=512) ======
__global__ __launch_bounds__(256) void bn_pool_kernel(
    const _Float16* __restrict__ h, const float* __restrict__ stats,
    const float* __restrict__ gamma, const float* __restrict__ beta,
    const int* __restrict__ batch, float* __restrict__ pooled, int N, float invN) {
  const int g = blockIdx.x >> 3;
  const int s = blockIdx.x & 7;
  __shared__ int s_lo, s_hi;
  if (threadIdx.x == 0) {
    int lo = 0, hi = N;
    while (lo < hi) { int m = (lo + hi) >> 1; if (batch[m] < g) lo = m + 1; else hi = m; }
    s_lo = lo;
    lo = 0; hi = N;
    while (lo < hi) { int m = (lo + hi) >> 1; if (batch[m] < g + 1) lo = m + 1; else hi = m; }
    s_hi = lo;
  }
  __syncthreads();
  const int lo = s_lo, hi = s_hi, len = hi - lo;
  if (len == 0) return;
  const int per = (len + 7) >> 3;
  const int rs = lo + s * per;
  const int re = min(rs + per, hi);
  if (rs >= re) return;
  const int t = threadIdx.x;
  float scv[2], shv[2];
#pragma unroll
  for (int j = 0; j < 2; j++) {
    int c = 2 * t + j;
    float mean = stats[c] * invN;
    float var = stats[512 + c] * invN - mean * mean;
    scv[j] = rsqrtf(var + 1e-5f) * gamma[c];
    shv[j] = beta[c] - mean * scv[j];
  }
  float ax = 0.f, ay = 0.f;
  for (int r = rs; r < re; r++) {
    f16x2 v = *(const f16x2*)(h + (size_t)r * 512 + 2 * t);
    ax += fmaxf((float)v[0] * scv[0] + shv[0], 0.f);
    ay += fmaxf((float)v[1] * scv[1] + shv[1], 0.f);
  }
  float inv = 1.f / (float)len;
  atomicAdd(&pooled[g * 512 + 2 * t], ax * inv);
  atomicAdd(&pooled[g * 512 + 2 * t + 1], ay * inv);
}

// ================= final projection =================
__global__ __launch_bounds__(64) void out_kernel(const float* __restrict__ pooled,
                                                 const float* __restrict__ wo,
                                                 const float* __restrict__ bo,
                                                 float* __restrict__ out) {
  int g = blockIdx.x, o = threadIdx.x;
  float acc = bo[o];
  for (int c = 0; c < 512; c++) acc += pooled[g * 512 + c] * wo[c * 64 + o];
  out[g * 64 + o] = fmaxf(acc, 0.f);
}

extern "C" void kernel_launch(void* const* d_in, const int* in_sizes, int n_in,
                              void* d_out, int out_size, void* d_ws, size_t ws_size,
                              hipStream_t stream) {
  const float* x0 = (const float*)d_in[0];
  const int* ei = (const int*)d_in[1];
  const int* batch = (const int*)d_in[2];
  const int N = in_sizes[0] / 128;
  const int E = in_sizes[1] / 2;
  const int* src = ei;
  const int* dst = ei + E;
  const float* W[3][6];
  for (int li = 0; li < 3; li++)
    for (int k = 0; k < 6; k++) W[li][k] = (const float*)d_in[3 + li * 6 + k];
  const float* wo = (const float*)d_in[21];
  const float* bo = (const float*)d_in[22];
  float* out = (float*)d_out;

  // workspace layout
  float* stats3 = (float*)d_ws;              // 3*1024
  float* pooled = stats3 + 3 * 1024;         // 64*512
  int* deg = (int*)(pooled + 64 * 512);      // N
  int* rowstart = deg + N;                   // N+1
  int* cursor = rowstart + N + 1;            // N
  int* nbr = cursor + N;                     // E
  uintptr_t wp = (uintptr_t)(nbr + E);
  wp = (wp + 15) & ~(uintptr_t)15;
  _Float16* aggh = (_Float16*)wp;            // N*256 f16
  _Float16* h1h = aggh + (size_t)N * 256;    // N*512 f16
  _Float16* h2h = h1h + (size_t)N * 512;     // N*512 f16
  _Float16* x0h = h2h + (size_t)N * 512;     // N*128 f16
  _Float16* wbuf = x0h + (size_t)N * 128;

  const int dins[3] = {128, 128, 256};
  const int douts[3] = {128, 256, 512};

  _Float16* WT[3][2];
  {
    _Float16* p = wbuf;
    for (int li = 0; li < 3; li++) {
      WT[li][0] = p; p += (size_t)dins[li] * douts[li];
      WT[li][1] = p; p += (size_t)douts[li] * douts[li];
    }
  }
  // batched weight prep (1 launch, fragment-linear output)
  {
    WAll wa;
    int maxTotal = 0;
    for (int li = 0; li < 3; li++) {
      int e1 = dins[li] * douts[li];
      int e2 = douts[li] * douts[li];
      wa.s[li * 2 + 0] = WSeg{W[li][0], WT[li][0], dins[li], douts[li], e1};
      wa.s[li * 2 + 1] = WSeg{W[li][2], WT[li][1], douts[li], douts[li], e2};
      maxTotal = max(maxTotal, max(e1, e2));
    }
    dim3 g((maxTotal + 255) / 256, 6);
    wprep_all_kernel<<<g, 256, 0, stream>>>(wa);
  }

  // x0 -> fp16, fused with zeroing deg + stats/pooled
  {
    int n4 = N * 32;
    int zn = 3 * 1024 + 64 * 512;
    xprep_kernel<<<(n4 + 255) / 256, 256, 0, stream>>>(
        (const float4*)x0, (f16x4*)x0h, n4, deg, N, stats3, zn);
  }

  // CSR build
  hist_kernel<<<(E + 255) / 256, 256, 0, stream>>>(dst, deg, E);
  scan_kernel<<<1, 1024, 0, stream>>>(deg, rowstart, cursor, N);
  fill_kernel<<<(E + 255) / 256, 256, 0, stream>>>(src, dst, cursor, nbr, E);

  const int mb64 = (N + 63) / 64;
  const int mb64_8 = ((mb64 + 7) / 8) * 8;
  const int mb32 = (N + 31) / 32;
  const int mb32_8 = ((mb32 + 7) / 8) * 8;
  const int gblocks = (N + 3) / 4;
  const float invN = 1.0f / N;

  for (int li = 0; li < 3; li++) {
    int Din = dins[li], Dout = douts[li];
    float* stats = stats3 + li * 1024;
    if (li == 0)
      gather_agg_kernel<2, false><<<gblocks, 256, 0, stream>>>(
          x0h, rowstart, nbr, nullptr, nullptr, nullptr, aggh, N, invN);
    else if (li == 1)
      gather_agg_kernel<2, true><<<gblocks, 256, 0, stream>>>(
          h2h, rowstart, nbr, stats3 + 0 * 1024, W[0][4], W[0][5], aggh, N, invN);
    else
      gather_agg_kernel<4, true><<<gblocks, 256, 0, stream>>>(
          h2h, rowstart, nbr, stats3 + 1 * 1024, W[1][4], W[1][5], aggh, N, invN);

    if (Dout == 128) {
      gemm_mfma_kernel<32><<<mb32_8, 256, 0, stream>>>(aggh, WT[li][0], W[li][1], h1h,
                                                       N, Din, Dout, mb32, 0, 1, nullptr);
      gemm_mfma_kernel<32><<<mb32_8, 256, 0, stream>>>(h1h, WT[li][1], W[li][3], h2h,
                                                       N, Dout, Dout, mb32, 0, 0, stats);
    } else {
      int cbShift = (Dout == 256) ? 1 : 2;
      int nblocks = mb64_8 << cbShift;
      gemm_mfma_kernel<64><<<nblocks, 256, 0, stream>>>(aggh, WT[li][0], W[li][1], h1h,
                                                        N, Din, Dout, mb64, cbShift, 1, nullptr);
      gemm_mfma_kernel<64><<<nblocks, 256, 0, stream>>>(h1h, WT[li][1], W[li][3], h2h,
                                                        N, Dout, Dout, mb64, cbShift, 0, stats);
    }
    if (li == 2) {
      bn_pool_kernel<<<64 * 8, 256, 0, stream>>>(
          h2h, stats3 + 2 * 1024, W[2][4], W[2][5], batch, pooled, N, invN);
    }
  }
  out_kernel<<<64, 64, 0, stream>>>(pooled, wo, bo, out);
}

// Round 24
// 266.477 us; speedup vs baseline: 1.2112x; 1.0004x over previous
//
#include <hip/hip_runtime.h>

typedef float f32x4 __attribute__((ext_vector_type(4)));
typedef _Float16 f16x2 __attribute__((ext_vector_type(2)));
typedef _Float16 f16x4 __attribute__((ext_vector_type(4)));
typedef _Float16 f16x8 __attribute__((ext_vector_type(8)));

// async global->LDS, 16B per lane; LDS dest = wave-uniform base + lane*16B
__device__ __forceinline__ void gload_lds16(const _Float16* g, _Float16* l) {
  __builtin_amdgcn_global_load_lds(
      (const __attribute__((address_space(1))) unsigned int*)g,
      (__attribute__((address_space(3))) unsigned int*)l, 16, 0, 0);
}

// ================= CSR build =================
__global__ __launch_bounds__(256) void hist_kernel(const int* __restrict__ dst,
                                                   int* __restrict__ deg, int E) {
  int e = blockIdx.x * 256 + threadIdx.x;
  if (e < E) atomicAdd(&deg[dst[e]], 1);
}

__global__ __launch_bounds__(1024) void scan_kernel(const int* __restrict__ deg,
                                                    int* __restrict__ rowstart,
                                                    int* __restrict__ cursor, int N) {
  __shared__ int sums[1024];
  const int t = threadIdx.x;
  const int CH = (N + 1023) >> 10;
  int local[32];
  int base = t * CH;
  int s = 0;
  for (int i = 0; i < CH; i++) {
    int idx = base + i;
    int v = (idx < N) ? deg[idx] : 0;
    local[i] = s;
    s += v;
  }
  sums[t] = s;
  __syncthreads();
  for (int off = 1; off < 1024; off <<= 1) {
    int add = (t >= off) ? sums[t - off] : 0;
    __syncthreads();
    sums[t] += add;
    __syncthreads();
  }
  int prefix = sums[t] - s;
  for (int i = 0; i < CH; i++) {
    int idx = base + i;
    if (idx < N) {
      int v = prefix + local[i];
      rowstart[idx] = v;
      cursor[idx] = v;
    }
  }
  if (t == 1023) rowstart[N] = sums[1023];
}

__global__ __launch_bounds__(256) void fill_kernel(const int* __restrict__ src,
                                                   const int* __restrict__ dst,
                                                   int* __restrict__ cursor,
                                                   int* __restrict__ nbr, int E) {
  int e = blockIdx.x * 256 + threadIdx.x;
  if (e >= E) return;
  int pos = atomicAdd(&cursor[dst[e]], 1);
  nbr[pos] = src[e];
}

// ========= x0 fp32 -> fp16, fused with zeroing deg + stats/pooled =========
__global__ __launch_bounds__(256) void xprep_kernel(const float4* __restrict__ in,
                                                    f16x4* __restrict__ out, int n4,
                                                    int* __restrict__ deg, int N,
                                                    float* __restrict__ zbuf, int zn) {
  int i = blockIdx.x * 256 + threadIdx.x;
  if (i < N) deg[i] = 0;
  if (i < zn) zbuf[i] = 0.f;
  if (i >= n4) return;
  float4 v = in[i];
  f16x4 h;
  h[0] = (_Float16)v.x; h[1] = (_Float16)v.y;
  h[2] = (_Float16)v.z; h[3] = (_Float16)v.w;
  out[i] = h;
}

// ====== gather over fp16 rows; BN fold + ReLU fused; FRAGMENT-LINEAR fp16 output ======
// agg frag layout: frag=(row>>4)*KT+(k>>5); slot=(row&15)|(((k>>3)&3)<<4); elem=k&7.
template <int C, bool BNIN>
__global__ __launch_bounds__(256) void gather_agg_kernel(
    const _Float16* __restrict__ x, const int* __restrict__ rowstart,
    const int* __restrict__ nbr, const float* __restrict__ stats,
    const float* __restrict__ gamma, const float* __restrict__ beta,
    _Float16* __restrict__ agg, int N, float invN) {
  constexpr int Din = 64 * C;
  constexpr int KT = Din >> 5;
  const int wave = threadIdx.x >> 6;
  const int lane = threadIdx.x & 63;
  const int node = blockIdx.x * 4 + wave;
  if (node >= N) return;

  float sc[C], sh[C];
  if constexpr (BNIN) {
#pragma unroll
    for (int j = 0; j < C; j++) {
      int c = lane * C + j;
      float mean = stats[c] * invN;
      float var = stats[Din + c] * invN - mean * mean;
      sc[j] = rsqrtf(var + 1e-5f) * gamma[c];
      sh[j] = beta[c] - mean * sc[j];
    }
  }

#define LOADROW(dstv, rowidx)                                              \
  {                                                                        \
    const _Float16* _p = x + (size_t)(rowidx)*Din + lane * C;              \
    if constexpr (C == 2) {                                                \
      f16x2 _t = *(const f16x2*)_p;                                        \
      dstv[0] = (float)_t[0]; dstv[1] = (float)_t[1];                      \
    } else {                                                               \
      f16x4 _t = *(const f16x4*)_p;                                        \
      dstv[0] = (float)_t[0]; dstv[1] = (float)_t[1];                      \
      dstv[2] = (float)_t[2]; dstv[3] = (float)_t[3];                      \
    }                                                                      \
  }
#define ACCUM(vv)                                                          \
  _Pragma("unroll") for (int j = 0; j < C; j++)                            \
      acc[j] += BNIN ? fmaxf(vv[j] * sc[j] + sh[j], 0.f) : vv[j];

  float acc[C];
  {
    float v[C];
    LOADROW(v, node)
#pragma unroll
    for (int j = 0; j < C; j++)
      acc[j] = BNIN ? fmaxf(v[j] * sc[j] + sh[j], 0.f) : v[j];
  }
  const int rs = rowstart[node], re = rowstart[node + 1];
  int e = rs;
  for (; e + 3 < re; e += 4) {
    int s0 = nbr[e], s1 = nbr[e + 1], s2 = nbr[e + 2], s3 = nbr[e + 3];
    float v0[C], v1[C], v2[C], v3[C];
    LOADROW(v0, s0)
    LOADROW(v1, s1)
    LOADROW(v2, s2)
    LOADROW(v3, s3)
    ACCUM(v0) ACCUM(v1) ACCUM(v2) ACCUM(v3)
  }
  for (; e + 1 < re; e += 2) {
    int s0 = nbr[e], s1 = nbr[e + 1];
    float v0[C], v1[C];
    LOADROW(v0, s0)
    LOADROW(v1, s1)
    ACCUM(v0) ACCUM(v1)
  }
  if (e < re) {
    int s0 = nbr[e];
    float v0[C];
    LOADROW(v0, s0)
    ACCUM(v0)
  }
#undef ACCUM
#undef LOADROW

  // fragment-linear store (r6-verified mapping)
  int kt, lc, jj;
  if constexpr (C == 4) {
    kt = lane >> 3; lc = (lane >> 1) & 3; jj = (lane & 1) * 4;
  } else {
    kt = lane >> 4; lc = (lane >> 2) & 3; jj = (lane & 3) * 2;
  }
  size_t addr = (((size_t)(node >> 4) * KT + kt)) * 512 +
                (size_t)((node & 15) | (lc << 4)) * 8 + jj;
  if constexpr (C == 2) {
    f16x2 r; r[0] = (_Float16)acc[0]; r[1] = (_Float16)acc[1];
    *(f16x2*)(agg + addr) = r;
  } else {
    f16x4 r;
    r[0] = (_Float16)acc[0]; r[1] = (_Float16)acc[1];
    r[2] = (_Float16)acc[2]; r[3] = (_Float16)acc[3];
    *(f16x4*)(agg + addr) = r;
  }
}

// ====== batched weight prep: W[K][N] fp32 -> fragment-linear fp16 B-tables ======
struct WSeg {
  const float* W;
  _Float16* TH;
  int K, N, total;
};
struct WAll { WSeg s[6]; };

__global__ __launch_bounds__(256) void wprep_all_kernel(WAll a) {
  WSeg sg = a.s[blockIdx.y];
  int idx = blockIdx.x * 256 + threadIdx.x;
  if (idx >= sg.total) return;
  int k = idx / sg.N, n = idx - k * sg.N;
  int KT = sg.K >> 5;
  int frag = (n >> 4) * KT + (k >> 5);
  int slot = (n & 15) | (((k >> 3) & 3) << 4);
  sg.TH[(size_t)frag * 512 + slot * 8 + (k & 7)] = (_Float16)sg.W[idx];
}

// ===== MFMA GEMM: all-FP16, fp32 accumulate; BOTH operands fragment-linear =====
// RT rows x 128 cols per block, 4 waves, BK=64; XCD swizzle.
// A staged via pure linear gload_lds DMA (1KB burst per fragment), 3 buffers,
// prefetch depth 2, B issued before stage (FIFO), raw s_barrier (no vmcnt(0) drain).
// FRAGOUT: relu(C+bias) written fragment-linear (next GEMM's A); else row-major + stats.
template <int RT, bool FRAGOUT>
__global__ __launch_bounds__(256, 4) void gemm_mfma_kernel(
    const _Float16* __restrict__ A, const _Float16* __restrict__ BT,
    const float* __restrict__ bias, _Float16* __restrict__ Ch,
    int M, int K, int N, int mblocks, int cbShift,
    int doRelu, float* __restrict__ stats) {
  constexpr int NF = RT / 16;   // row frags per 32-K half
  constexpr int NFT = 2 * NF;   // frags per 64-K step
  constexpr int FPW = NFT / 4;  // frags staged per wave (2 for RT=64, 1 for RT=32)
  __shared__ _Float16 Ah[3][NFT * 512];
  const int bid = blockIdx.x;
  const int xcd = bid & 7;
  const int q = bid >> 3;
  const int r = ((q >> cbShift) << 3) + xcd;
  const int cb = q & ((1 << cbShift) - 1);
  if (r >= mblocks) return;

  const int tid = threadIdx.x;
  const int lane = tid & 63;
  const int w = tid >> 6;
  const int rowBase = r * RT;
  const int colBase = cb * 128 + w * 32;
  const int KTa = K >> 5;  // k-frags in A row panels / B col tiles

  f32x4 acc[NF][2] = {};
  const int c0 = colBase + (lane & 15);
  // fragment-linear B bases for this wave's two col-tiles
  const size_t bBase0 = ((size_t)(colBase >> 4) * KTa) * 512 + (size_t)lane * 8;
  const size_t bBase1 = bBase0 + (size_t)KTa * 512;

  // fragment-linear A source bases (fully linear: frag base + lane*16B)
  size_t srcOff[FPW];
#pragma unroll
  for (int i = 0; i < FPW; i++) {
    int F = w * FPW + i;          // F = ks*NF + fi
    int ks = F / NF, fi = F % NF;
    srcOff[i] = (((size_t)((rowBase >> 4) + fi) * KTa) + ks) * 512 + (size_t)lane * 8;
  }

#define STAGE(b, t)                                                        \
  {                                                                        \
    _Pragma("unroll") for (int i = 0; i < FPW; i++)                        \
        gload_lds16(A + srcOff[i] + (size_t)(t) * 1024,                    \
                    &Ah[b][(w * FPW + i) * 512]);                          \
  }

  const int NT = K >> 6;
  STAGE(0, 0)
  if (NT > 1) {
    STAGE(1, 1)
    if constexpr (FPW == 2)
      asm volatile("s_waitcnt vmcnt(2)" ::: "memory");
    else
      asm volatile("s_waitcnt vmcnt(1)" ::: "memory");
  } else {
    asm volatile("s_waitcnt vmcnt(0)" ::: "memory");
  }
  __builtin_amdgcn_s_barrier();
  __builtin_amdgcn_sched_barrier(0);

  int cur = 0;
  for (int t = 0; t < NT; t++) {
    // 1) B fragments (contiguous 1KB wave loads), issued FIRST
    f16x8 bh[2][2];
#pragma unroll
    for (int ks = 0; ks < 2; ks++) {
      int kf = t * 2 + ks;
      bh[ks][0] = *(const f16x8*)(BT + bBase0 + (size_t)kf * 512);
      bh[ks][1] = *(const f16x8*)(BT + bBase1 + (size_t)kf * 512);
    }
    __builtin_amdgcn_sched_barrier(0);
    // 2) prefetch tile t+2 (newest in FIFO; survives B-wait and barrier)
    if (t + 2 < NT) {
      int b2 = (cur >= 1) ? cur - 1 : 2;  // (t+2)%3
      STAGE(b2, t + 2)
    }
    __builtin_amdgcn_sched_barrier(0);
    // 3) compute from Ah[cur]; B-wait retires stage(t+1) (FIFO), not t+2
#pragma unroll
    for (int ks = 0; ks < 2; ks++) {
#pragma unroll
      for (int fi = 0; fi < NF; fi++) {
        f16x8 ah = *(const f16x8*)(&Ah[cur][(ks * NF + fi) * 512 + lane * 8]);
        acc[fi][0] = __builtin_amdgcn_mfma_f32_16x16x32_f16(ah, bh[ks][0], acc[fi][0], 0, 0, 0);
        acc[fi][1] = __builtin_amdgcn_mfma_f32_16x16x32_f16(ah, bh[ks][1], acc[fi][1], 0, 0, 0);
      }
    }
    if (t + 1 < NT) {
      __builtin_amdgcn_s_barrier();       // raw barrier: no vmcnt(0) drain
      __builtin_amdgcn_sched_barrier(0);
    }
    cur = (cur == 2) ? 0 : cur + 1;
  }
#undef STAGE

  // epilogue
  const float bias0 = bias[c0], bias1 = bias[c0 + 16];
  if constexpr (FRAGOUT) {
    // write fragment-linear (padded alloc; tail rows land in valid scratch)
    const int KTo = N >> 5;
    const int row16b = (lane >> 4) * 4;  // row&15 base for j=0
    const int e0 = (lane & 15) & 7;
    const int lc0 = ((lane & 15) >> 3);       // (col>>3)&3 for c0
    const int kfo = (colBase >> 5);           // col>>5 (same for c0, c0+16)
#pragma unroll
    for (int fi = 0; fi < NF; fi++) {
      size_t fragRow = (size_t)((rowBase >> 4) + ((rowBase & 16) ? 0 : 0) + fi);
      // note: rowBase multiple of RT (32 or 64) -> rowBase>>4 aligned, +fi correct
      size_t base = ((size_t)((rowBase >> 4) + fi) * KTo + kfo) * 512;
#pragma unroll
      for (int j = 0; j < 4; j++) {
        int slotRow = row16b + j;
        float v0 = fmaxf(acc[fi][0][j] + bias0, 0.f);
        float v1 = fmaxf(acc[fi][1][j] + bias1, 0.f);
        Ch[base + (size_t)(slotRow | (lc0 << 4)) * 8 + e0] = (_Float16)v0;
        Ch[base + (size_t)(slotRow | ((lc0 + 2) << 4)) * 8 + e0] = (_Float16)v1;
      }
    }
  } else {
    float s1[2] = {0.f, 0.f}, s2[2] = {0.f, 0.f};
    const int rbase = rowBase + (lane >> 4) * 4;
#pragma unroll
    for (int fi = 0; fi < NF; fi++) {
#pragma unroll
      for (int j = 0; j < 4; j++) {
        int row = rbase + fi * 16 + j;
        float v0 = acc[fi][0][j] + bias0;
        float v1 = acc[fi][1][j] + bias1;
        if (doRelu) { v0 = fmaxf(v0, 0.f); v1 = fmaxf(v1, 0.f); }
        if (row < M) {
          Ch[(size_t)row * N + c0] = (_Float16)v0;
          Ch[(size_t)row * N + c0 + 16] = (_Float16)v1;
          s1[0] += v0; s2[0] += v0 * v0;
          s1[1] += v1; s2[1] += v1 * v1;
        }
      }
    }
    if (stats) {
#pragma unroll
      for (int off = 16; off < 64; off <<= 1) {
        s1[0] += __shfl_xor(s1[0], off);
        s2[0] += __shfl_xor(s2[0], off);
        s1[1] += __shfl_xor(s1[1], off);
        s2[1] += __shfl_xor(s2[1], off);
      }
      if (lane < 16) {
        atomicAdd(&stats[c0], s1[0]);
        atomicAdd(&stats[N + c0], s2[0]);
        atomicAdd(&stats[c0 + 16], s1[1]);
        atomicAdd(&stats[N + c0 + 16], s2[1]);
      }
    }
  }
}

// ====== fused BN(fold from raw sums)+ReLU+segment-mean pool (layer 3, D=512) ======
__global__ __launch_bounds__(256) void bn_pool_kernel(
    const _Float16* __restrict__ h, const float* __restrict__ stats,
    const float* __restrict__ gamma, const float* __restrict__ beta,
    const int* __restrict__ batch, float* __restrict__ pooled, int N, float invN) {
  const int g = blockIdx.x >> 3;
  const int s = blockIdx.x & 7;
  __shared__ int s_lo, s_hi;
  if (threadIdx.x == 0) {
    int lo = 0, hi = N;
    while (lo < hi) { int m = (lo + hi) >> 1; if (batch[m] < g) lo = m + 1; else hi = m; }
    s_lo = lo;
    lo = 0; hi = N;
    while (lo < hi) { int m = (lo + hi) >> 1; if (batch[m] < g + 1) lo = m + 1; else hi = m; }
    s_hi = lo;
  }
  __syncthreads();
  const int lo = s_lo, hi = s_hi, len = hi - lo;
  if (len == 0) return;
  const int per = (len + 7) >> 3;
  const int rs = lo + s * per;
  const int re = min(rs + per, hi);
  if (rs >= re) return;
  const int t = threadIdx.x;
  float scv[2], shv[2];
#pragma unroll
  for (int j = 0; j < 2; j++) {
    int c = 2 * t + j;
    float mean = stats[c] * invN;
    float var = stats[512 + c] * invN - mean * mean;
    scv[j] = rsqrtf(var + 1e-5f) * gamma[c];
    shv[j] = beta[c] - mean * scv[j];
  }
  float ax = 0.f, ay = 0.f;
  for (int r = rs; r < re; r++) {
    f16x2 v = *(const f16x2*)(h + (size_t)r * 512 + 2 * t);
    ax += fmaxf((float)v[0] * scv[0] + shv[0], 0.f);
    ay += fmaxf((float)v[1] * scv[1] + shv[1], 0.f);
  }
  float inv = 1.f / (float)len;
  atomicAdd(&pooled[g * 512 + 2 * t], ax * inv);
  atomicAdd(&pooled[g * 512 + 2 * t + 1], ay * inv);
}

// ================= final projection =================
__global__ __launch_bounds__(64) void out_kernel(const float* __restrict__ pooled,
                                                 const float* __restrict__ wo,
                                                 const float* __restrict__ bo,
                                                 float* __restrict__ out) {
  int g = blockIdx.x, o = threadIdx.x;
  float acc = bo[o];
  for (int c = 0; c < 512; c++) acc += pooled[g * 512 + c] * wo[c * 64 + o];
  out[g * 64 + o] = fmaxf(acc, 0.f);
}

extern "C" void kernel_launch(void* const* d_in, const int* in_sizes, int n_in,
                              void* d_out, int out_size, void* d_ws, size_t ws_size,
                              hipStream_t stream) {
  const float* x0 = (const float*)d_in[0];
  const int* ei = (const int*)d_in[1];
  const int* batch = (const int*)d_in[2];
  const int N = in_sizes[0] / 128;
  const int E = in_sizes[1] / 2;
  const int* src = ei;
  const int* dst = ei + E;
  const float* W[3][6];
  for (int li = 0; li < 3; li++)
    for (int k = 0; k < 6; k++) W[li][k] = (const float*)d_in[3 + li * 6 + k];
  const float* wo = (const float*)d_in[21];
  const float* bo = (const float*)d_in[22];
  float* out = (float*)d_out;

  const int mb64 = (N + 63) / 64;
  const int NP = mb64 * 64;  // padded rows for fragment-linear buffers

  // workspace layout
  float* stats3 = (float*)d_ws;              // 3*1024
  float* pooled = stats3 + 3 * 1024;         // 64*512
  int* deg = (int*)(pooled + 64 * 512);      // N
  int* rowstart = deg + N;                   // N+1
  int* cursor = rowstart + N + 1;            // N
  int* nbr = cursor + N;                     // E
  uintptr_t wp = (uintptr_t)(nbr + E);
  wp = (wp + 15) & ~(uintptr_t)15;
  _Float16* aggh = (_Float16*)wp;            // NP*256 f16 (fragment-linear)
  _Float16* h1h = aggh + (size_t)NP * 256;   // NP*512 f16 (fragment-linear)
  _Float16* h2h = h1h + (size_t)NP * 512;    // N*512 f16 (row-major)
  _Float16* x0h = h2h + (size_t)N * 512;     // N*128 f16 (row-major)
  _Float16* wbuf = x0h + (size_t)N * 128;

  const int dins[3] = {128, 128, 256};
  const int douts[3] = {128, 256, 512};

  _Float16* WT[3][2];
  {
    _Float16* p = wbuf;
    for (int li = 0; li < 3; li++) {
      WT[li][0] = p; p += (size_t)dins[li] * douts[li];
      WT[li][1] = p; p += (size_t)douts[li] * douts[li];
    }
  }
  // batched weight prep (1 launch, fragment-linear output)
  {
    WAll wa;
    int maxTotal = 0;
    for (int li = 0; li < 3; li++) {
      int e1 = dins[li] * douts[li];
      int e2 = douts[li] * douts[li];
      wa.s[li * 2 + 0] = WSeg{W[li][0], WT[li][0], dins[li], douts[li], e1};
      wa.s[li * 2 + 1] = WSeg{W[li][2], WT[li][1], douts[li], douts[li], e2};
      maxTotal = max(maxTotal, max(e1, e2));
    }
    dim3 g((maxTotal + 255) / 256, 6);
    wprep_all_kernel<<<g, 256, 0, stream>>>(wa);
  }

  // x0 -> fp16, fused with zeroing deg + stats/pooled
  {
    int n4 = N * 32;
    int zn = 3 * 1024 + 64 * 512;
    xprep_kernel<<<(n4 + 255) / 256, 256, 0, stream>>>(
        (const float4*)x0, (f16x4*)x0h, n4, deg, N, stats3, zn);
  }

  // CSR build
  hist_kernel<<<(E + 255) / 256, 256, 0, stream>>>(dst, deg, E);
  scan_kernel<<<1, 1024, 0, stream>>>(deg, rowstart, cursor, N);
  fill_kernel<<<(E + 255) / 256, 256, 0, stream>>>(src, dst, cursor, nbr, E);

  const int mb64_8 = ((mb64 + 7) / 8) * 8;
  const int mb32 = (N + 31) / 32;
  const int mb32_8 = ((mb32 + 7) / 8) * 8;
  const int gblocks = (N + 3) / 4;
  const float invN = 1.0f / N;

  for (int li = 0; li < 3; li++) {
    int Din = dins[li], Dout = douts[li];
    float* stats = stats3 + li * 1024;
    if (li == 0)
      gather_agg_kernel<2, false><<<gblocks, 256, 0, stream>>>(
          x0h, rowstart, nbr, nullptr, nullptr, nullptr, aggh, N, invN);
    else if (li == 1)
      gather_agg_kernel<2, true><<<gblocks, 256, 0, stream>>>(
          h2h, rowstart, nbr, stats3 + 0 * 1024, W[0][4], W[0][5], aggh, N, invN);
    else
      gather_agg_kernel<4, true><<<gblocks, 256, 0, stream>>>(
          h2h, rowstart, nbr, stats3 + 1 * 1024, W[1][4], W[1][5], aggh, N, invN);

    if (Dout == 128) {
      gemm_mfma_kernel<32, true><<<mb32_8, 256, 0, stream>>>(aggh, WT[li][0], W[li][1], h1h,
                                                             N, Din, Dout, mb32, 0, 1, nullptr);
      gemm_mfma_kernel<32, false><<<mb32_8, 256, 0, stream>>>(h1h, WT[li][1], W[li][3], h2h,
                                                              N, Dout, Dout, mb32, 0, 0, stats);
    } else {
      int cbShift = (Dout == 256) ? 1 : 2;
      int nblocks = mb64_8 << cbShift;
      gemm_mfma_kernel<64, true><<<nblocks, 256, 0, stream>>>(aggh, WT[li][0], W[li][1], h1h,
                                                              N, Din, Dout, mb64, cbShift, 1, nullptr);
      gemm_mfma_kernel<64, false><<<nblocks, 256, 0, stream>>>(h1h, WT[li][1], W[li][3], h2h,
                                                               N, Dout, Dout, mb64, cbShift, 0, stats);
    }
    if (li == 2) {
      bn_pool_kernel<<<64 * 8, 256, 0, stream>>>(
          h2h, stats3 + 2 * 1024, W[2][4], W[2][5], batch, pooled, N, invN);
    }
  }
  out_kernel<<<64, 64, 0, stream>>>(pooled, wo, bo, out);
}

// Round 25
// 265.903 us; speedup vs baseline: 1.2139x; 1.0022x over previous
//
#include <hip/hip_runtime.h>

typedef float f32x4 __attribute__((ext_vector_type(4)));
typedef _Float16 f16x2 __attribute__((ext_vector_type(2)));
typedef _Float16 f16x4 __attribute__((ext_vector_type(4)));
typedef _Float16 f16x8 __attribute__((ext_vector_type(8)));

// async global->LDS, 16B per lane; LDS dest = wave-uniform base + lane*16B
__device__ __forceinline__ void gload_lds16(const _Float16* g, _Float16* l) {
  __builtin_amdgcn_global_load_lds(
      (const __attribute__((address_space(1))) unsigned int*)g,
      (__attribute__((address_space(3))) unsigned int*)l, 16, 0, 0);
}

// ================= CSR build =================
__global__ __launch_bounds__(256) void hist_kernel(const int* __restrict__ dst,
                                                   int* __restrict__ deg, int E) {
  int e = blockIdx.x * 256 + threadIdx.x;
  if (e < E) atomicAdd(&deg[dst[e]], 1);
}

__global__ __launch_bounds__(1024) void scan_kernel(const int* __restrict__ deg,
                                                    int* __restrict__ rowstart,
                                                    int* __restrict__ cursor, int N) {
  __shared__ int sums[1024];
  const int t = threadIdx.x;
  const int CH = (N + 1023) >> 10;
  int local[32];
  int base = t * CH;
  int s = 0;
  for (int i = 0; i < CH; i++) {
    int idx = base + i;
    int v = (idx < N) ? deg[idx] : 0;
    local[i] = s;
    s += v;
  }
  sums[t] = s;
  __syncthreads();
  for (int off = 1; off < 1024; off <<= 1) {
    int add = (t >= off) ? sums[t - off] : 0;
    __syncthreads();
    sums[t] += add;
    __syncthreads();
  }
  int prefix = sums[t] - s;
  for (int i = 0; i < CH; i++) {
    int idx = base + i;
    if (idx < N) {
      int v = prefix + local[i];
      rowstart[idx] = v;
      cursor[idx] = v;
    }
  }
  if (t == 1023) rowstart[N] = sums[1023];
}

__global__ __launch_bounds__(256) void fill_kernel(const int* __restrict__ src,
                                                   const int* __restrict__ dst,
                                                   int* __restrict__ cursor,
                                                   int* __restrict__ nbr, int E) {
  int e = blockIdx.x * 256 + threadIdx.x;
  if (e >= E) return;
  int pos = atomicAdd(&cursor[dst[e]], 1);
  nbr[pos] = src[e];
}

// ========= x0 fp32 -> fp16, fused with zeroing deg + stats/pooled =========
__global__ __launch_bounds__(256) void xprep_kernel(const float4* __restrict__ in,
                                                    f16x4* __restrict__ out, int n4,
                                                    int* __restrict__ deg, int N,
                                                    float* __restrict__ zbuf, int zn) {
  int i = blockIdx.x * 256 + threadIdx.x;
  if (i < N) deg[i] = 0;
  if (i < zn) zbuf[i] = 0.f;
  if (i >= n4) return;
  float4 v = in[i];
  f16x4 h;
  h[0] = (_Float16)v.x; h[1] = (_Float16)v.y;
  h[2] = (_Float16)v.z; h[3] = (_Float16)v.w;
  out[i] = h;
}

// ====== gather over fp16 rows; BN fold + ReLU fused; FRAGMENT-LINEAR fp16 output ======
template <int C, bool BNIN>
__global__ __launch_bounds__(256) void gather_agg_kernel(
    const _Float16* __restrict__ x, const int* __restrict__ rowstart,
    const int* __restrict__ nbr, const float* __restrict__ stats,
    const float* __restrict__ gamma, const float* __restrict__ beta,
    _Float16* __restrict__ agg, int N, float invN) {
  constexpr int Din = 64 * C;
  constexpr int KT = Din >> 5;
  const int wave = threadIdx.x >> 6;
  const int lane = threadIdx.x & 63;
  const int node = blockIdx.x * 4 + wave;
  if (node >= N) return;

  float sc[C], sh[C];
  if constexpr (BNIN) {
#pragma unroll
    for (int j = 0; j < C; j++) {
      int c = lane * C + j;
      float mean = stats[c] * invN;
      float var = stats[Din + c] * invN - mean * mean;
      sc[j] = rsqrtf(var + 1e-5f) * gamma[c];
      sh[j] = beta[c] - mean * sc[j];
    }
  }

#define LOADROW(dstv, rowidx)                                              \
  {                                                                        \
    const _Float16* _p = x + (size_t)(rowidx)*Din + lane * C;              \
    if constexpr (C == 2) {                                                \
      f16x2 _t = *(const f16x2*)_p;                                        \
      dstv[0] = (float)_t[0]; dstv[1] = (float)_t[1];                      \
    } else {                                                               \
      f16x4 _t = *(const f16x4*)_p;                                        \
      dstv[0] = (float)_t[0]; dstv[1] = (float)_t[1];                      \
      dstv[2] = (float)_t[2]; dstv[3] = (float)_t[3];                      \
    }                                                                      \
  }
#define ACCUM(vv)                                                          \
  _Pragma("unroll") for (int j = 0; j < C; j++)                            \
      acc[j] += BNIN ? fmaxf(vv[j] * sc[j] + sh[j], 0.f) : vv[j];

  float acc[C];
  {
    float v[C];
    LOADROW(v, node)
#pragma unroll
    for (int j = 0; j < C; j++)
      acc[j] = BNIN ? fmaxf(v[j] * sc[j] + sh[j], 0.f) : v[j];
  }
  const int rs = rowstart[node], re = rowstart[node + 1];
  int e = rs;
  for (; e + 3 < re; e += 4) {
    int s0 = nbr[e], s1 = nbr[e + 1], s2 = nbr[e + 2], s3 = nbr[e + 3];
    float v0[C], v1[C], v2[C], v3[C];
    LOADROW(v0, s0)
    LOADROW(v1, s1)
    LOADROW(v2, s2)
    LOADROW(v3, s3)
    ACCUM(v0) ACCUM(v1) ACCUM(v2) ACCUM(v3)
  }
  for (; e + 1 < re; e += 2) {
    int s0 = nbr[e], s1 = nbr[e + 1];
    float v0[C], v1[C];
    LOADROW(v0, s0)
    LOADROW(v1, s1)
    ACCUM(v0) ACCUM(v1)
  }
  if (e < re) {
    int s0 = nbr[e];
    float v0[C];
    LOADROW(v0, s0)
    ACCUM(v0)
  }
#undef ACCUM
#undef LOADROW

  // fragment-linear store (r6-verified mapping)
  int kt, lc, jj;
  if constexpr (C == 4) {
    kt = lane >> 3; lc = (lane >> 1) & 3; jj = (lane & 1) * 4;
  } else {
    kt = lane >> 4; lc = (lane >> 2) & 3; jj = (lane & 3) * 2;
  }
  size_t addr = (((size_t)(node >> 4) * KT + kt)) * 512 +
                (size_t)((node & 15) | (lc << 4)) * 8 + jj;
  if constexpr (C == 2) {
    f16x2 r; r[0] = (_Float16)acc[0]; r[1] = (_Float16)acc[1];
    *(f16x2*)(agg + addr) = r;
  } else {
    f16x4 r;
    r[0] = (_Float16)acc[0]; r[1] = (_Float16)acc[1];
    r[2] = (_Float16)acc[2]; r[3] = (_Float16)acc[3];
    *(f16x4*)(agg + addr) = r;
  }
}

// ====== batched weight prep: W[K][N] fp32 -> fragment-linear fp16 B-tables ======
struct WSeg {
  const float* W;
  _Float16* TH;
  int K, N, total;
};
struct WAll { WSeg s[6]; };

__global__ __launch_bounds__(256) void wprep_all_kernel(WAll a) {
  WSeg sg = a.s[blockIdx.y];
  int idx = blockIdx.x * 256 + threadIdx.x;
  if (idx >= sg.total) return;
  int k = idx / sg.N, n = idx - k * sg.N;
  int KT = sg.K >> 5;
  int frag = (n >> 4) * KT + (k >> 5);
  int slot = (n & 15) | (((k >> 3) & 3) << 4);
  sg.TH[(size_t)frag * 512 + slot * 8 + (k & 7)] = (_Float16)sg.W[idx];
}

// ===== MFMA GEMM: all-FP16, fp32 accumulate; BOTH operands fragment-linear =====
// RT rows x 128 cols per block, 4 waves, BK=64; XCD swizzle.
// Pipeline: A via gload_lds (3 buffers, depth 2); B register-double-buffered (loaded
// one step ahead). Per step: vmcnt(FPW) retires own B(t)+stage(t), s_barrier gives
// cross-wave visibility of stage(t); MFMAs then run with ZERO in-step memory waits.
template <int RT, bool FRAGOUT>
__global__ __launch_bounds__(256, 4) void gemm_mfma_kernel(
    const _Float16* __restrict__ A, const _Float16* __restrict__ BT,
    const float* __restrict__ bias, _Float16* __restrict__ Ch,
    int M, int K, int N, int mblocks, int cbShift,
    int doRelu, float* __restrict__ stats) {
  constexpr int NF = RT / 16;   // row frags per 32-K half
  constexpr int NFT = 2 * NF;   // frags per 64-K step
  constexpr int FPW = NFT / 4;  // frags staged per wave (2 for RT=64, 1 for RT=32)
  __shared__ _Float16 Ah[3][NFT * 512];
  const int bid = blockIdx.x;
  const int xcd = bid & 7;
  const int q = bid >> 3;
  const int r = ((q >> cbShift) << 3) + xcd;
  const int cb = q & ((1 << cbShift) - 1);
  if (r >= mblocks) return;

  const int tid = threadIdx.x;
  const int lane = tid & 63;
  const int w = tid >> 6;
  const int rowBase = r * RT;
  const int colBase = cb * 128 + w * 32;
  const int KTa = K >> 5;  // k-frags in A row panels / B col tiles

  f32x4 acc[NF][2] = {};
  const int c0 = colBase + (lane & 15);
  // fragment-linear B bases for this wave's two col-tiles
  const size_t bBase0 = ((size_t)(colBase >> 4) * KTa) * 512 + (size_t)lane * 8;
  const size_t bBase1 = bBase0 + (size_t)KTa * 512;

  // fragment-linear A source bases (fully linear: frag base + lane*16B)
  size_t srcOff[FPW];
#pragma unroll
  for (int i = 0; i < FPW; i++) {
    int F = w * FPW + i;          // F = ks*NF + fi
    int ks = F / NF, fi = F % NF;
    srcOff[i] = (((size_t)((rowBase >> 4) + fi) * KTa) + ks) * 512 + (size_t)lane * 8;
  }

#define STAGE(b, t)                                                        \
  {                                                                        \
    _Pragma("unroll") for (int i = 0; i < FPW; i++)                        \
        gload_lds16(A + srcOff[i] + (size_t)(t) * 1024,                    \
                    &Ah[b][(w * FPW + i) * 512]);                          \
  }
#define LOADB(dst, t)                                                     \
  {                                                                       \
    _Pragma("unroll") for (int ks = 0; ks < 2; ks++) {                    \
      int kf = (t) * 2 + ks;                                              \
      dst[ks][0] = *(const f16x8*)(BT + bBase0 + (size_t)kf * 512);       \
      dst[ks][1] = *(const f16x8*)(BT + bBase1 + (size_t)kf * 512);       \
    }                                                                     \
  }

  const int NT = K >> 6;  // 2, 4 or 8 -- always even
  f16x8 bA[2][2], bB[2][2];
  // prologue: stage(0) first, then B(0), then stage(1) -> step-0 wait vmcnt(FPW)
  // leaves exactly stage(1) in flight, retiring stage(0) and B(0).
  STAGE(0, 0)
  LOADB(bA, 0)
  if (NT > 1) STAGE(1, 1)

  int cur = 0;
#define STEP(t, bcur, bnxt)                                                \
  {                                                                        \
    if ((t) == NT - 1) {                                                   \
      asm volatile("s_waitcnt vmcnt(0)" ::: "memory");                     \
    } else if constexpr (FPW == 2) {                                       \
      asm volatile("s_waitcnt vmcnt(2)" ::: "memory");                     \
    } else {                                                               \
      asm volatile("s_waitcnt vmcnt(1)" ::: "memory");                     \
    }                                                                      \
    __builtin_amdgcn_sched_barrier(0);                                     \
    __builtin_amdgcn_s_barrier();                                          \
    __builtin_amdgcn_sched_barrier(0);                                     \
    if ((t) + 1 < NT) LOADB(bnxt, (t) + 1)                                 \
    __builtin_amdgcn_sched_barrier(0);                                     \
    if ((t) + 2 < NT) {                                                    \
      int b2 = (cur >= 1) ? cur - 1 : 2; /* (t+2)%3 */                     \
      STAGE(b2, (t) + 2)                                                   \
    }                                                                      \
    __builtin_amdgcn_sched_barrier(0);                                     \
    _Pragma("unroll") for (int ks = 0; ks < 2; ks++) {                     \
      _Pragma("unroll") for (int fi = 0; fi < NF; fi++) {                  \
        f16x8 ah = *(const f16x8*)(&Ah[cur][(ks * NF + fi) * 512 + lane * 8]); \
        acc[fi][0] =                                                       \
            __builtin_amdgcn_mfma_f32_16x16x32_f16(ah, bcur[ks][0], acc[fi][0], 0, 0, 0); \
        acc[fi][1] =                                                       \
            __builtin_amdgcn_mfma_f32_16x16x32_f16(ah, bcur[ks][1], acc[fi][1], 0, 0, 0); \
      }                                                                    \
    }                                                                      \
    cur = (cur == 2) ? 0 : cur + 1;                                        \
  }

  for (int t = 0; t < NT; t += 2) {
    STEP(t, bA, bB)
    STEP(t + 1, bB, bA)
  }
#undef STEP
#undef LOADB
#undef STAGE

  // epilogue
  const float bias0 = bias[c0], bias1 = bias[c0 + 16];
  if constexpr (FRAGOUT) {
    // write fragment-linear (padded alloc; tail rows land in valid scratch)
    const int KTo = N >> 5;
    const int row16b = (lane >> 4) * 4;
    const int e0 = (lane & 15) & 7;
    const int lc0 = ((lane & 15) >> 3);
    const int kfo = (colBase >> 5);
#pragma unroll
    for (int fi = 0; fi < NF; fi++) {
      size_t base = ((size_t)((rowBase >> 4) + fi) * KTo + kfo) * 512;
#pragma unroll
      for (int j = 0; j < 4; j++) {
        int slotRow = row16b + j;
        float v0 = fmaxf(acc[fi][0][j] + bias0, 0.f);
        float v1 = fmaxf(acc[fi][1][j] + bias1, 0.f);
        Ch[base + (size_t)(slotRow | (lc0 << 4)) * 8 + e0] = (_Float16)v0;
        Ch[base + (size_t)(slotRow | ((lc0 + 2) << 4)) * 8 + e0] = (_Float16)v1;
      }
    }
  } else {
    float s1[2] = {0.f, 0.f}, s2[2] = {0.f, 0.f};
    const int rbase = rowBase + (lane >> 4) * 4;
#pragma unroll
    for (int fi = 0; fi < NF; fi++) {
#pragma unroll
      for (int j = 0; j < 4; j++) {
        int row = rbase + fi * 16 + j;
        float v0 = acc[fi][0][j] + bias0;
        float v1 = acc[fi][1][j] + bias1;
        if (doRelu) { v0 = fmaxf(v0, 0.f); v1 = fmaxf(v1, 0.f); }
        if (row < M) {
          Ch[(size_t)row * N + c0] = (_Float16)v0;
          Ch[(size_t)row * N + c0 + 16] = (_Float16)v1;
          s1[0] += v0; s2[0] += v0 * v0;
          s1[1] += v1; s2[1] += v1 * v1;
        }
      }
    }
    if (stats) {
#pragma unroll
      for (int off = 16; off < 64; off <<= 1) {
        s1[0] += __shfl_xor(s1[0], off);
        s2[0] += __shfl_xor(s2[0], off);
        s1[1] += __shfl_xor(s1[1], off);
        s2[1] += __shfl_xor(s2[1], off);
      }
      if (lane < 16) {
        atomicAdd(&stats[c0], s1[0]);
        atomicAdd(&stats[N + c0], s2[0]);
        atomicAdd(&stats[c0 + 16], s1[1]);
        atomicAdd(&stats[N + c0 + 16], s2[1]);
      }
    }
  }
}

// ====== fused BN(fold from raw sums)+ReLU+segment-mean pool (layer 3, D=512) ======
__global__ __launch_bounds__(256) void bn_pool_kernel(
    const _Float16* __restrict__ h, const float* __restrict__ stats,
    const float* __restrict__ gamma, const float* __restrict__ beta,
    const int* __restrict__ batch, float* __restrict__ pooled, int N, float invN) {
  const int g = blockIdx.x >> 3;
  const int s = blockIdx.x & 7;
  __shared__ int s_lo, s_hi;
  if (threadIdx.x == 0) {
    int lo = 0, hi = N;
    while (lo < hi) { int m = (lo + hi) >> 1; if (batch[m] < g) lo = m + 1; else hi = m; }
    s_lo = lo;
    lo = 0; hi = N;
    while (lo < hi) { int m = (lo + hi) >> 1; if (batch[m] < g + 1) lo = m + 1; else hi = m; }
    s_hi = lo;
  }
  __syncthreads();
  const int lo = s_lo, hi = s_hi, len = hi - lo;
  if (len == 0) return;
  const int per = (len + 7) >> 3;
  const int rs = lo + s * per;
  const int re = min(rs + per, hi);
  if (rs >= re) return;
  const int t = threadIdx.x;
  float scv[2], shv[2];
#pragma unroll
  for (int j = 0; j < 2; j++) {
    int c = 2 * t + j;
    float mean = stats[c] * invN;
    float var = stats[512 + c] * invN - mean * mean;
    scv[j] = rsqrtf(var + 1e-5f) * gamma[c];
    shv[j] = beta[c] - mean * scv[j];
  }
  float ax = 0.f, ay = 0.f;
  for (int r = rs; r < re; r++) {
    f16x2 v = *(const f16x2*)(h + (size_t)r * 512 + 2 * t);
    ax += fmaxf((float)v[0] * scv[0] + shv[0], 0.f);
    ay += fmaxf((float)v[1] * scv[1] + shv[1], 0.f);
  }
  float inv = 1.f / (float)len;
  atomicAdd(&pooled[g * 512 + 2 * t], ax * inv);
  atomicAdd(&pooled[g * 512 + 2 * t + 1], ay * inv);
}

// ================= final projection =================
__global__ __launch_bounds__(64) void out_kernel(const float* __restrict__ pooled,
                                                 const float* __restrict__ wo,
                                                 const float* __restrict__ bo,
                                                 float* __restrict__ out) {
  int g = blockIdx.x, o = threadIdx.x;
  float acc = bo[o];
  for (int c = 0; c < 512; c++) acc += pooled[g * 512 + c] * wo[c * 64 + o];
  out[g * 64 + o] = fmaxf(acc, 0.f);
}

extern "C" void kernel_launch(void* const* d_in, const int* in_sizes, int n_in,
                              void* d_out, int out_size, void* d_ws, size_t ws_size,
                              hipStream_t stream) {
  const float* x0 = (const float*)d_in[0];
  const int* ei = (const int*)d_in[1];
  const int* batch = (const int*)d_in[2];
  const int N = in_sizes[0] / 128;
  const int E = in_sizes[1] / 2;
  const int* src = ei;
  const int* dst = ei + E;
  const float* W[3][6];
  for (int li = 0; li < 3; li++)
    for (int k = 0; k < 6; k++) W[li][k] = (const float*)d_in[3 + li * 6 + k];
  const float* wo = (const float*)d_in[21];
  const float* bo = (const float*)d_in[22];
  float* out = (float*)d_out;

  const int mb64 = (N + 63) / 64;
  const int NP = mb64 * 64;  // padded rows for fragment-linear buffers

  // workspace layout
  float* stats3 = (float*)d_ws;              // 3*1024
  float* pooled = stats3 + 3 * 1024;         // 64*512
  int* deg = (int*)(pooled + 64 * 512);      // N
  int* rowstart = deg + N;                   // N+1
  int* cursor = rowstart + N + 1;            // N
  int* nbr = cursor + N;                     // E
  uintptr_t wp = (uintptr_t)(nbr + E);
  wp = (wp + 15) & ~(uintptr_t)15;
  _Float16* aggh = (_Float16*)wp;            // NP*256 f16 (fragment-linear)
  _Float16* h1h = aggh + (size_t)NP * 256;   // NP*512 f16 (fragment-linear)
  _Float16* h2h = h1h + (size_t)NP * 512;    // N*512 f16 (row-major)
  _Float16* x0h = h2h + (size_t)N * 512;     // N*128 f16 (row-major)
  _Float16* wbuf = x0h + (size_t)N * 128;

  const int dins[3] = {128, 128, 256};
  const int douts[3] = {128, 256, 512};

  _Float16* WT[3][2];
  {
    _Float16* p = wbuf;
    for (int li = 0; li < 3; li++) {
      WT[li][0] = p; p += (size_t)dins[li] * douts[li];
      WT[li][1] = p; p += (size_t)douts[li] * douts[li];
    }
  }
  // batched weight prep (1 launch, fragment-linear output)
  {
    WAll wa;
    int maxTotal = 0;
    for (int li = 0; li < 3; li++) {
      int e1 = dins[li] * douts[li];
      int e2 = douts[li] * douts[li];
      wa.s[li * 2 + 0] = WSeg{W[li][0], WT[li][0], dins[li], douts[li], e1};
      wa.s[li * 2 + 1] = WSeg{W[li][2], WT[li][1], douts[li], douts[li], e2};
      maxTotal = max(maxTotal, max(e1, e2));
    }
    dim3 g((maxTotal + 255) / 256, 6);
    wprep_all_kernel<<<g, 256, 0, stream>>>(wa);
  }

  // x0 -> fp16, fused with zeroing deg + stats/pooled
  {
    int n4 = N * 32;
    int zn = 3 * 1024 + 64 * 512;
    xprep_kernel<<<(n4 + 255) / 256, 256, 0, stream>>>(
        (const float4*)x0, (f16x4*)x0h, n4, deg, N, stats3, zn);
  }

  // CSR build
  hist_kernel<<<(E + 255) / 256, 256, 0, stream>>>(dst, deg, E);
  scan_kernel<<<1, 1024, 0, stream>>>(deg, rowstart, cursor, N);
  fill_kernel<<<(E + 255) / 256, 256, 0, stream>>>(src, dst, cursor, nbr, E);

  const int mb64_8 = ((mb64 + 7) / 8) * 8;
  const int mb32 = (N + 31) / 32;
  const int mb32_8 = ((mb32 + 7) / 8) * 8;
  const int gblocks = (N + 3) / 4;
  const float invN = 1.0f / N;

  for (int li = 0; li < 3; li++) {
    int Din = dins[li], Dout = douts[li];
    float* stats = stats3 + li * 1024;
    if (li == 0)
      gather_agg_kernel<2, false><<<gblocks, 256, 0, stream>>>(
          x0h, rowstart, nbr, nullptr, nullptr, nullptr, aggh, N, invN);
    else if (li == 1)
      gather_agg_kernel<2, true><<<gblocks, 256, 0, stream>>>(
          h2h, rowstart, nbr, stats3 + 0 * 1024, W[0][4], W[0][5], aggh, N, invN);
    else
      gather_agg_kernel<4, true><<<gblocks, 256, 0, stream>>>(
          h2h, rowstart, nbr, stats3 + 1 * 1024, W[1][4], W[1][5], aggh, N, invN);

    if (Dout == 128) {
      gemm_mfma_kernel<32, true><<<mb32_8, 256, 0, stream>>>(aggh, WT[li][0], W[li][1], h1h,
                                                             N, Din, Dout, mb32, 0, 1, nullptr);
      gemm_mfma_kernel<32, false><<<mb32_8, 256, 0, stream>>>(h1h, WT[li][1], W[li][3], h2h,
                                                              N, Dout, Dout, mb32, 0, 0, stats);
    } else {
      int cbShift = (Dout == 256) ? 1 : 2;
      int nblocks = mb64_8 << cbShift;
      gemm_mfma_kernel<64, true><<<nblocks, 256, 0, stream>>>(aggh, WT[li][0], W[li][1], h1h,
                                                              N, Din, Dout, mb64, cbShift, 1, nullptr);
      gemm_mfma_kernel<64, false><<<nblocks, 256, 0, stream>>>(h1h, WT[li][1], W[li][3], h2h,
                                                               N, Dout, Dout, mb64, cbShift, 0, stats);
    }
    if (li == 2) {
      bn_pool_kernel<<<64 * 8, 256, 0, stream>>>(
          h2h, stats3 + 2 * 1024, W[2][4], W[2][5], batch, pooled, N, invN);
    }
  }
  out_kernel<<<64, 64, 0, stream>>>(pooled, wo, bo, out);
}